// Round 1
// baseline (2331.769 us; speedup 1.0000x reference)
//
#include <hip/hip_runtime.h>
#include <math.h>

// Problem constants
#define SEQ 4096
#define LL  4097           // sequence + CLS
#define HDIM 32
#define NHEAD 8
#define HD 4
#define FFD 2048
#define NLAYER 6
#define EPSLN 1e-5f
#define NCHUNK 8           // split-K chunks over keys for attention
#define CHUNK 513          // ceil(4097/8)

// ---------------- embed: relu(feats @ lin_w.T + lin_b) + PE, CLS row = -1 ----
__global__ __launch_bounds__(256) void k_embed(const float* __restrict__ data,
    const float* __restrict__ lin_w, const float* __restrict__ lin_b,
    float* __restrict__ x) {
  int idx = blockIdx.x * 256 + threadIdx.x;   // idx = row*32 + h
  if (idx >= LL * HDIM) return;
  int row = idx >> 5, h = idx & 31;
  if (row == 0) { x[idx] = -1.0f; return; }
  int s = row - 1;
  float ts = data[s * 3 + 0];
  float f0 = data[s * 3 + 1];
  float f1 = data[s * 3 + 2];
  float lin = f0 * lin_w[h * 2 + 0] + f1 * lin_w[h * 2 + 1] + lin_b[h];
  lin = fmaxf(lin, 0.0f);
  // ts_idx = int32(ts / 100.0) -- keep true fp32 division to match numpy rounding
  int tsi = (int)(ts / 100.0f);
  int j = h >> 1;
  // div_j = exp(fp32(2j) * fp32(-log(1e4)/32)); double exp -> correctly rounded f32
  float aj = (float)(2 * j) * (float)(-0.28782313662425575);
  float divj = (float)exp((double)aj);
  float ang = (float)tsi * divj;
  float pe = (h & 1) ? cosf(ang) : sinf(ang);
  x[idx] = lin + pe;
}

// ---------------- qkv = x @ qkv_w.T + qkv_b  ([L,32]x[32,96]) ----------------
__global__ __launch_bounds__(256) void k_qkv(const float* __restrict__ x,
    const float* __restrict__ w, const float* __restrict__ b,
    float* __restrict__ qkv) {
  int idx = blockIdx.x * 256 + threadIdx.x;   // idx = row*96 + ch
  if (idx >= LL * 96) return;
  int row = idx / 96, ch = idx - row * 96;
  const float4* xr = (const float4*)(x + row * HDIM);
  const float4* wr = (const float4*)(w + ch * HDIM);
  float acc = b[ch];
#pragma unroll
  for (int k = 0; k < 8; ++k) {
    float4 xv = xr[k], wv = wr[k];
    acc = fmaf(xv.x, wv.x, acc);
    acc = fmaf(xv.y, wv.y, acc);
    acc = fmaf(xv.z, wv.z, acc);
    acc = fmaf(xv.w, wv.w, acc);
  }
  qkv[idx] = acc;
}

// ---------------- attention partials: flash over one key chunk ---------------
// grid (17 qtiles, 8 heads, 8 chunks), 256 thr; thread = one query.
// partial record per (c,q,h): {m, l, acc[4]}
__global__ __launch_bounds__(256) void k_attn(const float* __restrict__ qkv,
    float* __restrict__ part) {
  int tid = threadIdx.x;
  int h = blockIdx.y;
  int c = blockIdx.z;
  int q = blockIdx.x * 256 + tid;
  __shared__ float4 kt[128];
  __shared__ float4 vt[128];
  float4 qv = make_float4(0.f, 0.f, 0.f, 0.f);
  if (q < LL) qv = *(const float4*)(qkv + (size_t)q * 96 + h * HD);
  int k0 = c * CHUNK;
  int k1 = min(k0 + CHUNK, LL);
  float m = -1e30f, l = 0.f, a0 = 0.f, a1 = 0.f, a2 = 0.f, a3 = 0.f;
  for (int kb = k0; kb < k1; kb += 128) {
    int n = min(128, k1 - kb);
    __syncthreads();
    if (tid < n)
      kt[tid] = *(const float4*)(qkv + (size_t)(kb + tid) * 96 + 32 + h * HD);
    int t2 = tid - 128;
    if (t2 >= 0 && t2 < n)
      vt[t2] = *(const float4*)(qkv + (size_t)(kb + t2) * 96 + 64 + h * HD);
    __syncthreads();
    for (int j0 = 0; j0 < n; j0 += 8) {
      int jn = min(8, n - j0);
      float s[8];
#pragma unroll
      for (int jj = 0; jj < 8; ++jj) {
        float4 kv = kt[j0 + jj];
        float sc = 0.5f * (qv.x * kv.x + qv.y * kv.y + qv.z * kv.z + qv.w * kv.w);
        s[jj] = (jj < jn) ? sc : -1e30f;
      }
      float tm = s[0];
#pragma unroll
      for (int jj = 1; jj < 8; ++jj) tm = fmaxf(tm, s[jj]);
      float mn = fmaxf(m, tm);
      float alpha = __expf(m - mn);
      l *= alpha; a0 *= alpha; a1 *= alpha; a2 *= alpha; a3 *= alpha;
#pragma unroll
      for (int jj = 0; jj < 8; ++jj) {
        float p = (jj < jn) ? __expf(s[jj] - mn) : 0.f;
        float4 vv = vt[j0 + jj];
        l += p;
        a0 = fmaf(p, vv.x, a0);
        a1 = fmaf(p, vv.y, a1);
        a2 = fmaf(p, vv.z, a2);
        a3 = fmaf(p, vv.w, a3);
      }
      m = mn;
    }
  }
  if (q < LL) {
    float* p = part + (((size_t)c * LL + q) * NHEAD + h) * 6;
    p[0] = m; p[1] = l; p[2] = a0; p[3] = a1; p[4] = a2; p[5] = a3;
  }
}

// ---------------- combine split-K partials -> attno [L,32] -------------------
__global__ __launch_bounds__(256) void k_comb(const float* __restrict__ part,
    float* __restrict__ attno) {
  int idx = blockIdx.x * 256 + threadIdx.x;   // idx = q*8 + h
  if (idx >= LL * NHEAD) return;
  int q = idx >> 3, h = idx & 7;
  float M = -1e30f;
#pragma unroll
  for (int c = 0; c < NCHUNK; ++c)
    M = fmaxf(M, part[(((size_t)c * LL + q) * NHEAD + h) * 6]);
  float L = 0.f, A0 = 0.f, A1 = 0.f, A2 = 0.f, A3 = 0.f;
#pragma unroll
  for (int c = 0; c < NCHUNK; ++c) {
    const float* p = part + (((size_t)c * LL + q) * NHEAD + h) * 6;
    float w = __expf(p[0] - M);
    L = fmaf(p[1], w, L);
    A0 = fmaf(p[2], w, A0);
    A1 = fmaf(p[3], w, A1);
    A2 = fmaf(p[4], w, A2);
    A3 = fmaf(p[5], w, A3);
  }
  float inv = 1.f / L;
  float* o = attno + (size_t)q * HDIM + h * HD;
  o[0] = A0 * inv; o[1] = A1 * inv; o[2] = A2 * inv; o[3] = A3 * inv;
}

// ---------------- o-proj + residual + LN1 (in-place on x) --------------------
// 256 thr = 8 rows x 32 lanes; LN via width-32 shuffles.
__global__ __launch_bounds__(256) void k_oproj(const float* __restrict__ attno,
    float* __restrict__ x, const float* __restrict__ ow,
    const float* __restrict__ ob, const float* __restrict__ g,
    const float* __restrict__ bln) {
  int tid = threadIdx.x;
  int r = tid >> 5, ch = tid & 31;
  int row = blockIdx.x * 8 + r;
  __shared__ float os[8][32];
  bool ok = row < LL;
  if (ok) os[r][ch] = attno[(size_t)row * HDIM + ch];
  __syncthreads();
  float acc = 0.f;
#pragma unroll
  for (int k = 0; k < 32; ++k) acc = fmaf(os[r][k], ow[ch * 32 + k], acc);
  float val = ok ? (x[(size_t)row * HDIM + ch] + acc + ob[ch]) : 0.f;
  float mean = val;
#pragma unroll
  for (int off = 16; off > 0; off >>= 1) mean += __shfl_xor(mean, off, 32);
  mean *= (1.f / 32.f);
  float d = val - mean;
  float var = d * d;
#pragma unroll
  for (int off = 16; off > 0; off >>= 1) var += __shfl_xor(var, off, 32);
  var *= (1.f / 32.f);
  float y = d / sqrtf(var + EPSLN) * g[ch] + bln[ch];
  if (ok) x[(size_t)row * HDIM + ch] = y;
}

// ---------------- fused FFN (ff1+relu+ff2) + residual + LN2, one row/block ---
__global__ __launch_bounds__(256) void k_ffn(float* __restrict__ x,
    const float* __restrict__ w1, const float* __restrict__ b1,
    const float* __restrict__ w2, const float* __restrict__ b2,
    const float* __restrict__ g, const float* __restrict__ bln) {
  __shared__ float xr[32];
  __shared__ float fr[FFD];
  __shared__ float ps[256];
  int row = blockIdx.x;
  int tid = threadIdx.x;
  if (tid < 32) xr[tid] = x[(size_t)row * HDIM + tid];
  __syncthreads();
  float xv[32];
#pragma unroll
  for (int k = 0; k < 32; ++k) xv[k] = xr[k];
  // FFN1: each thread 8 channels
#pragma unroll
  for (int j = 0; j < 8; ++j) {
    int ff = j * 256 + tid;
    const float4* w = (const float4*)(w1 + (size_t)ff * 32);
    float acc = b1[ff];
#pragma unroll
    for (int k = 0; k < 8; ++k) {
      float4 wv = w[k];
      acc = fmaf(xv[4 * k + 0], wv.x, acc);
      acc = fmaf(xv[4 * k + 1], wv.y, acc);
      acc = fmaf(xv[4 * k + 2], wv.z, acc);
      acc = fmaf(xv[4 * k + 3], wv.w, acc);
    }
    fr[ff] = fmaxf(acc, 0.f);
  }
  __syncthreads();
  // FFN2: 8-way split-K over 2048
  int ch = tid & 31, seg = tid >> 5;
  const float4* f4 = (const float4*)(fr + seg * 256);
  const float4* w4 = (const float4*)(w2 + (size_t)ch * FFD + seg * 256);
  float p = 0.f;
#pragma unroll 8
  for (int i = 0; i < 64; ++i) {
    float4 fv = f4[i], wv = w4[i];
    p = fmaf(fv.x, wv.x, p);
    p = fmaf(fv.y, wv.y, p);
    p = fmaf(fv.z, wv.z, p);
    p = fmaf(fv.w, wv.w, p);
  }
  ps[tid] = p;
  __syncthreads();
  if (tid < 32) {
    float s = 0.f;
#pragma unroll
    for (int q = 0; q < 8; ++q) s += ps[q * 32 + tid];
    float val = xr[tid] + s + b2[tid];
    float mean = val;
#pragma unroll
    for (int off = 16; off > 0; off >>= 1) mean += __shfl_xor(mean, off, 32);
    mean *= (1.f / 32.f);
    float d = val - mean;
    float var = d * d;
#pragma unroll
    for (int off = 16; off > 0; off >>= 1) var += __shfl_xor(var, off, 32);
    var *= (1.f / 32.f);
    float y = d / sqrtf(var + EPSLN) * g[tid] + bln[tid];
    x[(size_t)row * HDIM + tid] = y;
  }
}

// ---------------- final: sigmoid(x[0] . cls_w + cls_b) -----------------------
__global__ void k_final(const float* __restrict__ x, const float* __restrict__ cw,
                        const float* __restrict__ cb, float* __restrict__ out) {
  int t = threadIdx.x;   // 64 threads
  float v = (t < 32) ? x[t] * cw[t] : 0.f;
#pragma unroll
  for (int off = 32; off > 0; off >>= 1) v += __shfl_xor(v, off, 64);
  if (t == 0) {
    float z = v + cb[0];
    out[0] = 1.f / (1.f + expf(-z));
  }
}

extern "C" void kernel_launch(void* const* d_in, const int* in_sizes, int n_in,
                              void* d_out, int out_size, void* d_ws, size_t ws_size,
                              hipStream_t stream) {
  const float* data  = (const float*)d_in[0];
  const float* lin_w = (const float*)d_in[1];
  const float* lin_b = (const float*)d_in[2];
  const float* qkv_w = (const float*)d_in[3];
  const float* qkv_b = (const float*)d_in[4];
  const float* out_w = (const float*)d_in[5];
  const float* out_b = (const float*)d_in[6];
  const float* ln1_g = (const float*)d_in[7];
  const float* ln1_b = (const float*)d_in[8];
  const float* ff1_w = (const float*)d_in[9];
  const float* ff1_b = (const float*)d_in[10];
  const float* ff2_w = (const float*)d_in[11];
  const float* ff2_b = (const float*)d_in[12];
  const float* ln2_g = (const float*)d_in[13];
  const float* ln2_b = (const float*)d_in[14];
  const float* cls_w = (const float*)d_in[15];
  const float* cls_b = (const float*)d_in[16];

  float* ws = (float*)d_ws;
  float* X    = ws;                        // LL*32
  float* QKV  = X + (size_t)LL * 32;       // LL*96
  float* ATT  = QKV + (size_t)LL * 96;     // LL*32
  float* PART = ATT + (size_t)LL * 32;     // NCHUNK*LL*NHEAD*6

  k_embed<<<(LL * 32 + 255) / 256, 256, 0, stream>>>(data, lin_w, lin_b, X);
  for (int l = 0; l < NLAYER; ++l) {
    k_qkv<<<(LL * 96 + 255) / 256, 256, 0, stream>>>(
        X, qkv_w + (size_t)l * 96 * 32, qkv_b + (size_t)l * 96, QKV);
    k_attn<<<dim3(17, NHEAD, NCHUNK), 256, 0, stream>>>(QKV, PART);
    k_comb<<<(LL * NHEAD + 255) / 256, 256, 0, stream>>>(PART, ATT);
    k_oproj<<<(LL + 7) / 8, 256, 0, stream>>>(
        ATT, X, out_w + (size_t)l * 32 * 32, out_b + (size_t)l * 32,
        ln1_g + (size_t)l * 32, ln1_b + (size_t)l * 32);
    k_ffn<<<LL, 256, 0, stream>>>(
        X, ff1_w + (size_t)l * FFD * 32, ff1_b + (size_t)l * FFD,
        ff2_w + (size_t)l * 32 * FFD, ff2_b + (size_t)l * 32,
        ln2_g + (size_t)l * 32, ln2_b + (size_t)l * 32);
  }
  k_final<<<1, 64, 0, stream>>>(X, cls_w, cls_b, (float*)d_out);
}

// Round 2
// 862.396 us; speedup vs baseline: 2.7038x; 2.7038x over previous
//
#include <hip/hip_runtime.h>
#include <math.h>

// Problem constants
#define SEQ 4096
#define LL  4097           // sequence + CLS
#define HDIM 32
#define NHEAD 8
#define HD 4
#define FFD 2048
#define NLAYER 6
#define EPSLN 1e-5f
#define NCHUNK 8           // split-K chunks over keys for attention
#define CHUNK 513          // ceil(4097/8)
#define RT 64              // FFN row tile
#define FS 128             // FFN f-segment width
#define NFS 16             // FFD / FS

// ---------------- embed: relu(feats @ lin_w.T + lin_b) + PE, CLS row = -1 ----
__global__ __launch_bounds__(256) void k_embed(const float* __restrict__ data,
    const float* __restrict__ lin_w, const float* __restrict__ lin_b,
    float* __restrict__ x) {
  int idx = blockIdx.x * 256 + threadIdx.x;   // idx = row*32 + h
  if (idx >= LL * HDIM) return;
  int row = idx >> 5, h = idx & 31;
  if (row == 0) { x[idx] = -1.0f; return; }
  int s = row - 1;
  float ts = data[s * 3 + 0];
  float f0 = data[s * 3 + 1];
  float f1 = data[s * 3 + 2];
  float lin = f0 * lin_w[h * 2 + 0] + f1 * lin_w[h * 2 + 1] + lin_b[h];
  lin = fmaxf(lin, 0.0f);
  int tsi = (int)(ts / 100.0f);
  int j = h >> 1;
  float aj = (float)(2 * j) * (float)(-0.28782313662425575);
  float divj = (float)exp((double)aj);
  float ang = (float)tsi * divj;
  float pe = (h & 1) ? cosf(ang) : sinf(ang);
  x[idx] = lin + pe;
}

// ---------------- qkv = x @ qkv_w.T + qkv_b  ([L,32]x[32,96]) ----------------
__global__ __launch_bounds__(256) void k_qkv(const float* __restrict__ x,
    const float* __restrict__ w, const float* __restrict__ b,
    float* __restrict__ qkv) {
  int idx = blockIdx.x * 256 + threadIdx.x;   // idx = row*96 + ch
  if (idx >= LL * 96) return;
  int row = idx / 96, ch = idx - row * 96;
  const float4* xr = (const float4*)(x + row * HDIM);
  const float4* wr = (const float4*)(w + ch * HDIM);
  float acc = b[ch];
#pragma unroll
  for (int k = 0; k < 8; ++k) {
    float4 xv = xr[k], wv = wr[k];
    acc = fmaf(xv.x, wv.x, acc);
    acc = fmaf(xv.y, wv.y, acc);
    acc = fmaf(xv.z, wv.z, acc);
    acc = fmaf(xv.w, wv.w, acc);
  }
  qkv[idx] = acc;
}

// ---------------- attention partials: flash over one key chunk ---------------
__global__ __launch_bounds__(256) void k_attn(const float* __restrict__ qkv,
    float* __restrict__ part) {
  int tid = threadIdx.x;
  int h = blockIdx.y;
  int c = blockIdx.z;
  int q = blockIdx.x * 256 + tid;
  __shared__ float4 kt[128];
  __shared__ float4 vt[128];
  float4 qv = make_float4(0.f, 0.f, 0.f, 0.f);
  if (q < LL) qv = *(const float4*)(qkv + (size_t)q * 96 + h * HD);
  int k0 = c * CHUNK;
  int k1 = min(k0 + CHUNK, LL);
  float m = -1e30f, l = 0.f, a0 = 0.f, a1 = 0.f, a2 = 0.f, a3 = 0.f;
  for (int kb = k0; kb < k1; kb += 128) {
    int n = min(128, k1 - kb);
    __syncthreads();
    if (tid < n)
      kt[tid] = *(const float4*)(qkv + (size_t)(kb + tid) * 96 + 32 + h * HD);
    int t2 = tid - 128;
    if (t2 >= 0 && t2 < n)
      vt[t2] = *(const float4*)(qkv + (size_t)(kb + t2) * 96 + 64 + h * HD);
    __syncthreads();
    for (int j0 = 0; j0 < n; j0 += 8) {
      int jn = min(8, n - j0);
      float s[8];
#pragma unroll
      for (int jj = 0; jj < 8; ++jj) {
        float4 kv = kt[j0 + jj];
        float sc = 0.5f * (qv.x * kv.x + qv.y * kv.y + qv.z * kv.z + qv.w * kv.w);
        s[jj] = (jj < jn) ? sc : -1e30f;
      }
      float tm = s[0];
#pragma unroll
      for (int jj = 1; jj < 8; ++jj) tm = fmaxf(tm, s[jj]);
      float mn = fmaxf(m, tm);
      float alpha = __expf(m - mn);
      l *= alpha; a0 *= alpha; a1 *= alpha; a2 *= alpha; a3 *= alpha;
#pragma unroll
      for (int jj = 0; jj < 8; ++jj) {
        float p = (jj < jn) ? __expf(s[jj] - mn) : 0.f;
        float4 vv = vt[j0 + jj];
        l += p;
        a0 = fmaf(p, vv.x, a0);
        a1 = fmaf(p, vv.y, a1);
        a2 = fmaf(p, vv.z, a2);
        a3 = fmaf(p, vv.w, a3);
      }
      m = mn;
    }
  }
  if (q < LL) {
    float* p = part + (((size_t)c * LL + q) * NHEAD + h) * 6;
    p[0] = m; p[1] = l; p[2] = a0; p[3] = a1; p[4] = a2; p[5] = a3;
  }
}

// ---------------- combine split-K partials -> attno [L,32] -------------------
__global__ __launch_bounds__(256) void k_comb(const float* __restrict__ part,
    float* __restrict__ attno) {
  int idx = blockIdx.x * 256 + threadIdx.x;   // idx = q*8 + h
  if (idx >= LL * NHEAD) return;
  int q = idx >> 3, h = idx & 7;
  float M = -1e30f;
#pragma unroll
  for (int c = 0; c < NCHUNK; ++c)
    M = fmaxf(M, part[(((size_t)c * LL + q) * NHEAD + h) * 6]);
  float L = 0.f, A0 = 0.f, A1 = 0.f, A2 = 0.f, A3 = 0.f;
#pragma unroll
  for (int c = 0; c < NCHUNK; ++c) {
    const float* p = part + (((size_t)c * LL + q) * NHEAD + h) * 6;
    float w = __expf(p[0] - M);
    L = fmaf(p[1], w, L);
    A0 = fmaf(p[2], w, A0);
    A1 = fmaf(p[3], w, A1);
    A2 = fmaf(p[4], w, A2);
    A3 = fmaf(p[5], w, A3);
  }
  float inv = 1.f / L;
  float* o = attno + (size_t)q * HDIM + h * HD;
  o[0] = A0 * inv; o[1] = A1 * inv; o[2] = A2 * inv; o[3] = A3 * inv;
}

// ---------------- o-proj + residual + LN1 (in-place on x) --------------------
__global__ __launch_bounds__(256) void k_oproj(const float* __restrict__ attno,
    float* __restrict__ x, const float* __restrict__ ow,
    const float* __restrict__ ob, const float* __restrict__ g,
    const float* __restrict__ bln) {
  int tid = threadIdx.x;
  int r = tid >> 5, ch = tid & 31;
  int row = blockIdx.x * 8 + r;
  __shared__ float os[8][32];
  bool ok = row < LL;
  if (ok) os[r][ch] = attno[(size_t)row * HDIM + ch];
  __syncthreads();
  float acc = 0.f;
#pragma unroll
  for (int k = 0; k < 32; ++k) acc = fmaf(os[r][k], ow[ch * 32 + k], acc);
  float val = ok ? (x[(size_t)row * HDIM + ch] + acc + ob[ch]) : 0.f;
  float mean = val;
#pragma unroll
  for (int off = 16; off > 0; off >>= 1) mean += __shfl_xor(mean, off, 32);
  mean *= (1.f / 32.f);
  float d = val - mean;
  float var = d * d;
#pragma unroll
  for (int off = 16; off > 0; off >>= 1) var += __shfl_xor(var, off, 32);
  var *= (1.f / 32.f);
  float y = d / sqrtf(var + EPSLN) * g[ch] + bln[ch];
  if (ok) x[(size_t)row * HDIM + ch] = y;
}

// ---------------- fused FFN part A: per (row-tile, f-segment) ----------------
// f = relu(X[64,32] @ W1seg^T[32,128]); partial = f @ W2seg^T[128,32]
// partials written to part2[seg][row][32].
__global__ __launch_bounds__(256) void k_ffnA(const float* __restrict__ x,
    const float* __restrict__ w1, const float* __restrict__ b1,
    const float* __restrict__ w2, float* __restrict__ part2) {
  __shared__ float Xs[RT][33];      // +1 pad: conflict-free scalar reads
  __shared__ float W1t[32][132];    // k-major, 16B-aligned rows
  __shared__ float W2t[FS][36];     // k-major, 16B-aligned rows
  __shared__ float Fs[RT][129];     // +1 pad: 2-way (free) scalar reads
  int tid = threadIdx.x;
  int r0 = blockIdx.x * RT;
  int f0 = blockIdx.y * FS;

  // load Xs (2048 floats, coalesced, zero-pad tail rows)
#pragma unroll
  for (int p = 0; p < 8; ++p) {
    int idx = p * 256 + tid;
    int r = idx >> 5, k = idx & 31;
    Xs[r][k] = (r0 + r < LL) ? x[(size_t)(r0 + r) * HDIM + k] : 0.f;
  }
  // load W1 transposed: w1[(f0+c)*32+k] -> W1t[k][c]
#pragma unroll
  for (int p = 0; p < 16; ++p) {
    int idx = p * 256 + tid;
    int c = idx >> 5, k = idx & 31;
    W1t[k][c] = w1[(size_t)(f0 + c) * HDIM + k];
  }
  // load W2 transposed: w2[c*2048 + f0+k] -> W2t[k][c]
#pragma unroll
  for (int p = 0; p < 16; ++p) {
    int idx = p * 256 + tid;
    int c = idx >> 7, k = idx & 127;
    W2t[k][c] = w2[(size_t)c * FFD + f0 + k];
  }
  __syncthreads();

  // phase 1: thread = 4 rows (rg) x 8 cols (cg)
  int rg = tid >> 4, cg = tid & 15;
  float acc[4][8];
#pragma unroll
  for (int i = 0; i < 4; ++i)
#pragma unroll
    for (int j = 0; j < 8; ++j) acc[i][j] = 0.f;
#pragma unroll
  for (int k = 0; k < 32; ++k) {
    float xv[4];
#pragma unroll
    for (int i = 0; i < 4; ++i) xv[i] = Xs[rg * 4 + i][k];
    float4 w0 = *(const float4*)&W1t[k][cg * 8];
    float4 w1v = *(const float4*)&W1t[k][cg * 8 + 4];
#pragma unroll
    for (int i = 0; i < 4; ++i) {
      acc[i][0] = fmaf(xv[i], w0.x, acc[i][0]);
      acc[i][1] = fmaf(xv[i], w0.y, acc[i][1]);
      acc[i][2] = fmaf(xv[i], w0.z, acc[i][2]);
      acc[i][3] = fmaf(xv[i], w0.w, acc[i][3]);
      acc[i][4] = fmaf(xv[i], w1v.x, acc[i][4]);
      acc[i][5] = fmaf(xv[i], w1v.y, acc[i][5]);
      acc[i][6] = fmaf(xv[i], w1v.z, acc[i][6]);
      acc[i][7] = fmaf(xv[i], w1v.w, acc[i][7]);
    }
  }
  // bias + relu -> Fs
#pragma unroll
  for (int j = 0; j < 8; ++j) {
    float bb = b1[f0 + cg * 8 + j];
#pragma unroll
    for (int i = 0; i < 4; ++i)
      Fs[rg * 4 + i][cg * 8 + j] = fmaxf(acc[i][j] + bb, 0.f);
  }
  __syncthreads();

  // phase 2: thread = k-quarter (kq) x 4 rows (r4) x 8 cols (c8)
  int kq = tid >> 6, r4 = (tid >> 2) & 15, c8 = tid & 3;
  float a2[4][8];
#pragma unroll
  for (int i = 0; i < 4; ++i)
#pragma unroll
    for (int j = 0; j < 8; ++j) a2[i][j] = 0.f;
  int kbase = kq * 32;
#pragma unroll
  for (int kk = 0; kk < 32; ++kk) {
    int k = kbase + kk;
    float fv[4];
#pragma unroll
    for (int i = 0; i < 4; ++i) fv[i] = Fs[r4 * 4 + i][k];
    float4 u0 = *(const float4*)&W2t[k][c8 * 8];
    float4 u1 = *(const float4*)&W2t[k][c8 * 8 + 4];
#pragma unroll
    for (int i = 0; i < 4; ++i) {
      a2[i][0] = fmaf(fv[i], u0.x, a2[i][0]);
      a2[i][1] = fmaf(fv[i], u0.y, a2[i][1]);
      a2[i][2] = fmaf(fv[i], u0.z, a2[i][2]);
      a2[i][3] = fmaf(fv[i], u0.w, a2[i][3]);
      a2[i][4] = fmaf(fv[i], u1.x, a2[i][4]);
      a2[i][5] = fmaf(fv[i], u1.y, a2[i][5]);
      a2[i][6] = fmaf(fv[i], u1.z, a2[i][6]);
      a2[i][7] = fmaf(fv[i], u1.w, a2[i][7]);
    }
  }
  // combine the 4 k-quarters in LDS (reuse Xs[64][33] as Os[64][32])
  for (int q = 0; q < 4; ++q) {
    if (kq == q) {
#pragma unroll
      for (int i = 0; i < 4; ++i)
#pragma unroll
        for (int j = 0; j < 8; ++j) {
          int rr = r4 * 4 + i, cc = c8 * 8 + j;
          if (q == 0) Xs[rr][cc] = a2[i][j];
          else Xs[rr][cc] += a2[i][j];
        }
    }
    __syncthreads();
  }
  // write partial tile (coalesced)
#pragma unroll
  for (int p = 0; p < 8; ++p) {
    int idx = p * 256 + tid;
    int r = idx >> 5, cc = idx & 31;
    if (r0 + r < LL)
      part2[((size_t)blockIdx.y * LL + r0 + r) * HDIM + cc] = Xs[r][cc];
  }
}

// ---------------- FFN part B: combine segments + residual + LN2 --------------
__global__ __launch_bounds__(256) void k_ffnB(float* __restrict__ x,
    const float* __restrict__ part2, const float* __restrict__ b2,
    const float* __restrict__ g, const float* __restrict__ bln) {
  int tid = threadIdx.x;
  int r = tid >> 5, ch = tid & 31;
  int row = blockIdx.x * 8 + r;
  bool ok = row < LL;
  float s = 0.f;
  if (ok) {
#pragma unroll
    for (int q = 0; q < NFS; ++q)
      s += part2[((size_t)q * LL + row) * HDIM + ch];
  }
  float val = ok ? (x[(size_t)row * HDIM + ch] + s + b2[ch]) : 0.f;
  float mean = val;
#pragma unroll
  for (int off = 16; off > 0; off >>= 1) mean += __shfl_xor(mean, off, 32);
  mean *= (1.f / 32.f);
  float d = val - mean;
  float var = d * d;
#pragma unroll
  for (int off = 16; off > 0; off >>= 1) var += __shfl_xor(var, off, 32);
  var *= (1.f / 32.f);
  float y = d / sqrtf(var + EPSLN) * g[ch] + bln[ch];
  if (ok) x[(size_t)row * HDIM + ch] = y;
}

// ---------------- final: sigmoid(x[0] . cls_w + cls_b) -----------------------
__global__ void k_final(const float* __restrict__ x, const float* __restrict__ cw,
                        const float* __restrict__ cb, float* __restrict__ out) {
  int t = threadIdx.x;   // 64 threads
  float v = (t < 32) ? x[t] * cw[t] : 0.f;
#pragma unroll
  for (int off = 32; off > 0; off >>= 1) v += __shfl_xor(v, off, 64);
  if (t == 0) {
    float z = v + cb[0];
    out[0] = 1.f / (1.f + expf(-z));
  }
}

extern "C" void kernel_launch(void* const* d_in, const int* in_sizes, int n_in,
                              void* d_out, int out_size, void* d_ws, size_t ws_size,
                              hipStream_t stream) {
  const float* data  = (const float*)d_in[0];
  const float* lin_w = (const float*)d_in[1];
  const float* lin_b = (const float*)d_in[2];
  const float* qkv_w = (const float*)d_in[3];
  const float* qkv_b = (const float*)d_in[4];
  const float* out_w = (const float*)d_in[5];
  const float* out_b = (const float*)d_in[6];
  const float* ln1_g = (const float*)d_in[7];
  const float* ln1_b = (const float*)d_in[8];
  const float* ff1_w = (const float*)d_in[9];
  const float* ff1_b = (const float*)d_in[10];
  const float* ff2_w = (const float*)d_in[11];
  const float* ff2_b = (const float*)d_in[12];
  const float* ln2_g = (const float*)d_in[13];
  const float* ln2_b = (const float*)d_in[14];
  const float* cls_w = (const float*)d_in[15];
  const float* cls_b = (const float*)d_in[16];

  float* ws = (float*)d_ws;
  float* X     = ws;                          // LL*32
  float* QKV   = X + (size_t)LL * 32;         // LL*96
  float* ATT   = QKV + (size_t)LL * 96;       // LL*32
  float* PART  = ATT + (size_t)LL * 32;       // NCHUNK*LL*NHEAD*6
  float* PART2 = PART + (size_t)NCHUNK * LL * NHEAD * 6;  // NFS*LL*32

  k_embed<<<(LL * 32 + 255) / 256, 256, 0, stream>>>(data, lin_w, lin_b, X);
  for (int l = 0; l < NLAYER; ++l) {
    k_qkv<<<(LL * 96 + 255) / 256, 256, 0, stream>>>(
        X, qkv_w + (size_t)l * 96 * 32, qkv_b + (size_t)l * 96, QKV);
    k_attn<<<dim3(17, NHEAD, NCHUNK), 256, 0, stream>>>(QKV, PART);
    k_comb<<<(LL * NHEAD + 255) / 256, 256, 0, stream>>>(PART, ATT);
    k_oproj<<<(LL + 7) / 8, 256, 0, stream>>>(
        ATT, X, out_w + (size_t)l * 32 * 32, out_b + (size_t)l * 32,
        ln1_g + (size_t)l * 32, ln1_b + (size_t)l * 32);
    k_ffnA<<<dim3((LL + RT - 1) / RT, NFS), 256, 0, stream>>>(
        X, ff1_w + (size_t)l * FFD * 32, ff1_b + (size_t)l * FFD,
        ff2_w + (size_t)l * 32 * FFD, PART2);
    k_ffnB<<<(LL + 7) / 8, 256, 0, stream>>>(
        X, PART2, ff2_b + (size_t)l * 32,
        ln2_g + (size_t)l * 32, ln2_b + (size_t)l * 32);
  }
  k_final<<<1, 64, 0, stream>>>(X, cls_w, cls_b, (float*)d_out);
}

// Round 3
// 851.861 us; speedup vs baseline: 2.7373x; 1.0124x over previous
//
#include <hip/hip_runtime.h>
#include <math.h>

// Problem constants
#define SEQ 4096
#define LL  4097           // sequence + CLS
#define HDIM 32
#define NHEAD 8
#define HD 4
#define FFD 2048
#define NLAYER 6
#define EPSLN 1e-5f
#define NCHUNK 16          // split-K chunks over keys for attention
#define CHUNK 257          // ceil(4097/16)
#define QB 4               // queries per thread in k_attn
#define RT 64              // FFN row tile
#define FS 128             // FFN f-segment width
#define NFS 16             // FFD / FS

#if __has_builtin(__builtin_amdgcn_exp2f)
#define EXP2 __builtin_amdgcn_exp2f
#else
#define EXP2 exp2f
#endif

#define QSCALE 0.7213475204444817f   // 0.5 * log2(e): folds 1/sqrt(HD) and exp->exp2

__device__ __forceinline__ float dot4(float4 a, float4 b) {
  return fmaf(a.w, b.w, fmaf(a.z, b.z, fmaf(a.y, b.y, a.x * b.x)));
}

// ---------------- embed: relu(feats @ lin_w.T + lin_b) + PE, CLS row = -1 ----
__global__ __launch_bounds__(256) void k_embed(const float* __restrict__ data,
    const float* __restrict__ lin_w, const float* __restrict__ lin_b,
    float* __restrict__ x) {
  int idx = blockIdx.x * 256 + threadIdx.x;   // idx = row*32 + h
  if (idx >= LL * HDIM) return;
  int row = idx >> 5, h = idx & 31;
  if (row == 0) { x[idx] = -1.0f; return; }
  int s = row - 1;
  float ts = data[s * 3 + 0];
  float f0 = data[s * 3 + 1];
  float f1 = data[s * 3 + 2];
  float lin = f0 * lin_w[h * 2 + 0] + f1 * lin_w[h * 2 + 1] + lin_b[h];
  lin = fmaxf(lin, 0.0f);
  int tsi = (int)(ts / 100.0f);
  int j = h >> 1;
  float aj = (float)(2 * j) * (float)(-0.28782313662425575);
  float divj = (float)exp((double)aj);
  float ang = (float)tsi * divj;
  float pe = (h & 1) ? cosf(ang) : sinf(ang);
  x[idx] = lin + pe;
}

// ---------------- qkv = x @ qkv_w.T + qkv_b  ([L,32]x[32,96]) ----------------
__global__ __launch_bounds__(256) void k_qkv(const float* __restrict__ x,
    const float* __restrict__ w, const float* __restrict__ b,
    float* __restrict__ qkv) {
  int idx = blockIdx.x * 256 + threadIdx.x;   // idx = row*96 + ch
  if (idx >= LL * 96) return;
  int row = idx / 96, ch = idx - row * 96;
  const float4* xr = (const float4*)(x + row * HDIM);
  const float4* wr = (const float4*)(w + ch * HDIM);
  float acc = b[ch];
#pragma unroll
  for (int k = 0; k < 8; ++k) {
    float4 xv = xr[k], wv = wr[k];
    acc = fmaf(xv.x, wv.x, acc);
    acc = fmaf(xv.y, wv.y, acc);
    acc = fmaf(xv.z, wv.z, acc);
    acc = fmaf(xv.w, wv.w, acc);
  }
  qkv[idx] = acc;
}

// ---------------- attention partials (flash, split-K, QB queries/thread) -----
// grid (5, NHEAD, NCHUNK). blocks x<4: q = 1 + bx*1024 + i*256 + tid (exact
// cover of q=1..4096, no dead lanes). block x==4: CLS query (q=0), 64 lanes.
// partial record per (c,q,h): {m(log2 domain), l, acc[4]}
__global__ __launch_bounds__(256) void k_attn(const float* __restrict__ qkv,
    float* __restrict__ part) {
  int tid = threadIdx.x;
  int h = blockIdx.y;
  int c = blockIdx.z;
  int k0 = c * CHUNK;
  int k1 = min(k0 + CHUNK, LL);

  if (blockIdx.x == 4) {
    // ---- CLS path: one wave, keys strided by 64, shuffle-merge ----
    if (tid >= 64) return;
    float4 q = *(const float4*)(qkv + 0 * 96 + h * HD);
    q.x *= QSCALE; q.y *= QSCALE; q.z *= QSCALE; q.w *= QSCALE;
    float m = -1e30f, l = 0.f;
    float4 a = make_float4(0.f, 0.f, 0.f, 0.f);
    for (int k = k0 + tid; k < k1; k += 64) {
      float4 kv = *(const float4*)(qkv + (size_t)k * 96 + 32 + h * HD);
      float4 vv = *(const float4*)(qkv + (size_t)k * 96 + 64 + h * HD);
      float s = dot4(q, kv);
      float mn = fmaxf(m, s);
      float al = EXP2(m - mn);
      float p = EXP2(s - mn);
      l = fmaf(l, al, p);
      a.x = fmaf(a.x, al, p * vv.x);
      a.y = fmaf(a.y, al, p * vv.y);
      a.z = fmaf(a.z, al, p * vv.z);
      a.w = fmaf(a.w, al, p * vv.w);
      m = mn;
    }
#pragma unroll
    for (int off = 1; off < 64; off <<= 1) {
      float m2 = __shfl_xor(m, off, 64);
      float l2 = __shfl_xor(l, off, 64);
      float ax = __shfl_xor(a.x, off, 64);
      float ay = __shfl_xor(a.y, off, 64);
      float az = __shfl_xor(a.z, off, 64);
      float aw = __shfl_xor(a.w, off, 64);
      float mn = fmaxf(m, m2);
      float w1 = EXP2(m - mn), w2 = EXP2(m2 - mn);
      l = l * w1 + l2 * w2;
      a.x = a.x * w1 + ax * w2;
      a.y = a.y * w1 + ay * w2;
      a.z = a.z * w1 + az * w2;
      a.w = a.w * w1 + aw * w2;
      m = mn;
    }
    if (tid == 0) {
      float* p = part + (((size_t)c * LL + 0) * NHEAD + h) * 6;
      p[0] = m; p[1] = l; p[2] = a.x; p[3] = a.y; p[4] = a.z; p[5] = a.w;
    }
    return;
  }

  // ---- main path ----
  __shared__ float4 kt[128];
  __shared__ float4 vt[128];
  float4 qv[QB];
  float m[QB], l[QB];
  float4 a[QB];
#pragma unroll
  for (int i = 0; i < QB; ++i) {
    int q = 1 + blockIdx.x * 1024 + i * 256 + tid;   // always in [1,4096]
    float4 t = *(const float4*)(qkv + (size_t)q * 96 + h * HD);
    t.x *= QSCALE; t.y *= QSCALE; t.z *= QSCALE; t.w *= QSCALE;
    qv[i] = t;
    m[i] = -1e30f; l[i] = 0.f;
    a[i] = make_float4(0.f, 0.f, 0.f, 0.f);
  }

  for (int kb = k0; kb < k1; kb += 128) {
    int n = min(128, k1 - kb);
    __syncthreads();
    if (tid < n)
      kt[tid] = *(const float4*)(qkv + (size_t)(kb + tid) * 96 + 32 + h * HD);
    int t2 = tid - 128;
    if (t2 >= 0 && t2 < n)
      vt[t2] = *(const float4*)(qkv + (size_t)(kb + t2) * 96 + 64 + h * HD);
    __syncthreads();

    int nfull = n & ~7;
    for (int j0 = 0; j0 < nfull; j0 += 8) {
      float4 kk[8], vv[8];
#pragma unroll
      for (int jj = 0; jj < 8; ++jj) { kk[jj] = kt[j0 + jj]; vv[jj] = vt[j0 + jj]; }
#pragma unroll
      for (int i = 0; i < QB; ++i) {
        float s[8];
#pragma unroll
        for (int jj = 0; jj < 8; ++jj) s[jj] = dot4(qv[i], kk[jj]);
        float tm = s[0];
#pragma unroll
        for (int jj = 1; jj < 8; ++jj) tm = fmaxf(tm, s[jj]);
        float mn = fmaxf(m[i], tm);
        float al = EXP2(m[i] - mn);
        l[i] *= al;
        a[i].x *= al; a[i].y *= al; a[i].z *= al; a[i].w *= al;
        m[i] = mn;
#pragma unroll
        for (int jj = 0; jj < 8; ++jj) {
          float p = EXP2(s[jj] - mn);
          l[i] += p;
          a[i].x = fmaf(p, vv[jj].x, a[i].x);
          a[i].y = fmaf(p, vv[jj].y, a[i].y);
          a[i].z = fmaf(p, vv[jj].z, a[i].z);
          a[i].w = fmaf(p, vv[jj].w, a[i].w);
        }
      }
    }
    int jn = n - nfull;
    if (jn > 0) {
#pragma unroll
      for (int i = 0; i < QB; ++i) {
        float s[8];
        float4 vv[8];
#pragma unroll
        for (int jj = 0; jj < 8; ++jj) {
          if (jj < jn) {
            s[jj] = dot4(qv[i], kt[nfull + jj]);
            vv[jj] = vt[nfull + jj];
          } else {
            s[jj] = -1e30f;
            vv[jj] = make_float4(0.f, 0.f, 0.f, 0.f);
          }
        }
        float tm = s[0];
#pragma unroll
        for (int jj = 1; jj < 8; ++jj) tm = fmaxf(tm, s[jj]);
        float mn = fmaxf(m[i], tm);
        float al = EXP2(m[i] - mn);
        l[i] *= al;
        a[i].x *= al; a[i].y *= al; a[i].z *= al; a[i].w *= al;
        m[i] = mn;
#pragma unroll
        for (int jj = 0; jj < 8; ++jj) {
          float p = EXP2(s[jj] - mn);
          l[i] += p;
          a[i].x = fmaf(p, vv[jj].x, a[i].x);
          a[i].y = fmaf(p, vv[jj].y, a[i].y);
          a[i].z = fmaf(p, vv[jj].z, a[i].z);
          a[i].w = fmaf(p, vv[jj].w, a[i].w);
        }
      }
    }
  }

#pragma unroll
  for (int i = 0; i < QB; ++i) {
    int q = 1 + blockIdx.x * 1024 + i * 256 + tid;
    float* p = part + (((size_t)c * LL + q) * NHEAD + h) * 6;
    p[0] = m[i]; p[1] = l[i];
    p[2] = a[i].x; p[3] = a[i].y; p[4] = a[i].z; p[5] = a[i].w;
  }
}

// ------- fused: combine split-K partials + o-proj + residual + LN1 ----------
// 256 thr = 8 rows x 32 lanes. Phase A: lane = h*4+d combines 16 chunks for
// (row, h), writes os[r][h*4+d]. Phase B: o-proj + LN via width-32 shuffles.
__global__ __launch_bounds__(256) void k_oproj(const float* __restrict__ part,
    float* __restrict__ x, const float* __restrict__ ow,
    const float* __restrict__ ob, const float* __restrict__ g,
    const float* __restrict__ bln) {
  int tid = threadIdx.x;
  int r = tid >> 5, ch = tid & 31;
  int row = blockIdx.x * 8 + r;
  __shared__ float os[8][32];
  bool ok = row < LL;
  if (ok) {
    int h = ch >> 2, d = ch & 3;
    float M = -1e30f;
#pragma unroll
    for (int c = 0; c < NCHUNK; ++c)
      M = fmaxf(M, part[(((size_t)c * LL + row) * NHEAD + h) * 6]);
    float L = 0.f, A = 0.f;
#pragma unroll
    for (int c = 0; c < NCHUNK; ++c) {
      const float* p = part + (((size_t)c * LL + row) * NHEAD + h) * 6;
      float w = EXP2(p[0] - M);
      L = fmaf(p[1], w, L);
      A = fmaf(p[2 + d], w, A);
    }
    os[r][ch] = A / L;
  } else {
    os[r][ch] = 0.f;
  }
  __syncthreads();
  float acc = 0.f;
#pragma unroll
  for (int k = 0; k < 32; ++k) acc = fmaf(os[r][k], ow[ch * 32 + k], acc);
  float val = ok ? (x[(size_t)row * HDIM + ch] + acc + ob[ch]) : 0.f;
  float mean = val;
#pragma unroll
  for (int off = 16; off > 0; off >>= 1) mean += __shfl_xor(mean, off, 32);
  mean *= (1.f / 32.f);
  float d = val - mean;
  float var = d * d;
#pragma unroll
  for (int off = 16; off > 0; off >>= 1) var += __shfl_xor(var, off, 32);
  var *= (1.f / 32.f);
  float y = d / sqrtf(var + EPSLN) * g[ch] + bln[ch];
  if (ok) x[(size_t)row * HDIM + ch] = y;
}

// ---------------- fused FFN part A: per (row-tile, f-segment) ----------------
__global__ __launch_bounds__(256) void k_ffnA(const float* __restrict__ x,
    const float* __restrict__ w1, const float* __restrict__ b1,
    const float* __restrict__ w2, float* __restrict__ part2) {
  __shared__ float Xs[RT][33];
  __shared__ float W1t[32][132];
  __shared__ float W2t[FS][36];
  __shared__ float Fs[RT][129];
  int tid = threadIdx.x;
  int r0 = blockIdx.x * RT;
  int f0 = blockIdx.y * FS;

#pragma unroll
  for (int p = 0; p < 8; ++p) {
    int idx = p * 256 + tid;
    int r = idx >> 5, k = idx & 31;
    Xs[r][k] = (r0 + r < LL) ? x[(size_t)(r0 + r) * HDIM + k] : 0.f;
  }
#pragma unroll
  for (int p = 0; p < 16; ++p) {
    int idx = p * 256 + tid;
    int c = idx >> 5, k = idx & 31;
    W1t[k][c] = w1[(size_t)(f0 + c) * HDIM + k];
  }
#pragma unroll
  for (int p = 0; p < 16; ++p) {
    int idx = p * 256 + tid;
    int c = idx >> 7, k = idx & 127;
    W2t[k][c] = w2[(size_t)c * FFD + f0 + k];
  }
  __syncthreads();

  int rg = tid >> 4, cg = tid & 15;
  float acc[4][8];
#pragma unroll
  for (int i = 0; i < 4; ++i)
#pragma unroll
    for (int j = 0; j < 8; ++j) acc[i][j] = 0.f;
#pragma unroll
  for (int k = 0; k < 32; ++k) {
    float xv[4];
#pragma unroll
    for (int i = 0; i < 4; ++i) xv[i] = Xs[rg * 4 + i][k];
    float4 w0 = *(const float4*)&W1t[k][cg * 8];
    float4 w1v = *(const float4*)&W1t[k][cg * 8 + 4];
#pragma unroll
    for (int i = 0; i < 4; ++i) {
      acc[i][0] = fmaf(xv[i], w0.x, acc[i][0]);
      acc[i][1] = fmaf(xv[i], w0.y, acc[i][1]);
      acc[i][2] = fmaf(xv[i], w0.z, acc[i][2]);
      acc[i][3] = fmaf(xv[i], w0.w, acc[i][3]);
      acc[i][4] = fmaf(xv[i], w1v.x, acc[i][4]);
      acc[i][5] = fmaf(xv[i], w1v.y, acc[i][5]);
      acc[i][6] = fmaf(xv[i], w1v.z, acc[i][6]);
      acc[i][7] = fmaf(xv[i], w1v.w, acc[i][7]);
    }
  }
#pragma unroll
  for (int j = 0; j < 8; ++j) {
    float bb = b1[f0 + cg * 8 + j];
#pragma unroll
    for (int i = 0; i < 4; ++i)
      Fs[rg * 4 + i][cg * 8 + j] = fmaxf(acc[i][j] + bb, 0.f);
  }
  __syncthreads();

  int kq = tid >> 6, r4 = (tid >> 2) & 15, c8 = tid & 3;
  float a2[4][8];
#pragma unroll
  for (int i = 0; i < 4; ++i)
#pragma unroll
    for (int j = 0; j < 8; ++j) a2[i][j] = 0.f;
  int kbase = kq * 32;
#pragma unroll
  for (int kk = 0; kk < 32; ++kk) {
    int k = kbase + kk;
    float fv[4];
#pragma unroll
    for (int i = 0; i < 4; ++i) fv[i] = Fs[r4 * 4 + i][k];
    float4 u0 = *(const float4*)&W2t[k][c8 * 8];
    float4 u1 = *(const float4*)&W2t[k][c8 * 8 + 4];
#pragma unroll
    for (int i = 0; i < 4; ++i) {
      a2[i][0] = fmaf(fv[i], u0.x, a2[i][0]);
      a2[i][1] = fmaf(fv[i], u0.y, a2[i][1]);
      a2[i][2] = fmaf(fv[i], u0.z, a2[i][2]);
      a2[i][3] = fmaf(fv[i], u0.w, a2[i][3]);
      a2[i][4] = fmaf(fv[i], u1.x, a2[i][4]);
      a2[i][5] = fmaf(fv[i], u1.y, a2[i][5]);
      a2[i][6] = fmaf(fv[i], u1.z, a2[i][6]);
      a2[i][7] = fmaf(fv[i], u1.w, a2[i][7]);
    }
  }
  for (int q = 0; q < 4; ++q) {
    if (kq == q) {
#pragma unroll
      for (int i = 0; i < 4; ++i)
#pragma unroll
        for (int j = 0; j < 8; ++j) {
          int rr = r4 * 4 + i, cc = c8 * 8 + j;
          if (q == 0) Xs[rr][cc] = a2[i][j];
          else Xs[rr][cc] += a2[i][j];
        }
    }
    __syncthreads();
  }
#pragma unroll
  for (int p = 0; p < 8; ++p) {
    int idx = p * 256 + tid;
    int r = idx >> 5, cc = idx & 31;
    if (r0 + r < LL)
      part2[((size_t)blockIdx.y * LL + r0 + r) * HDIM + cc] = Xs[r][cc];
  }
}

// ---------------- FFN part B: combine segments + residual + LN2 --------------
__global__ __launch_bounds__(256) void k_ffnB(float* __restrict__ x,
    const float* __restrict__ part2, const float* __restrict__ b2,
    const float* __restrict__ g, const float* __restrict__ bln) {
  int tid = threadIdx.x;
  int r = tid >> 5, ch = tid & 31;
  int row = blockIdx.x * 8 + r;
  bool ok = row < LL;
  float s = 0.f;
  if (ok) {
#pragma unroll
    for (int q = 0; q < NFS; ++q)
      s += part2[((size_t)q * LL + row) * HDIM + ch];
  }
  float val = ok ? (x[(size_t)row * HDIM + ch] + s + b2[ch]) : 0.f;
  float mean = val;
#pragma unroll
  for (int off = 16; off > 0; off >>= 1) mean += __shfl_xor(mean, off, 32);
  mean *= (1.f / 32.f);
  float d = val - mean;
  float var = d * d;
#pragma unroll
  for (int off = 16; off > 0; off >>= 1) var += __shfl_xor(var, off, 32);
  var *= (1.f / 32.f);
  float y = d / sqrtf(var + EPSLN) * g[ch] + bln[ch];
  if (ok) x[(size_t)row * HDIM + ch] = y;
}

// ---------------- final: sigmoid(x[0] . cls_w + cls_b) -----------------------
__global__ void k_final(const float* __restrict__ x, const float* __restrict__ cw,
                        const float* __restrict__ cb, float* __restrict__ out) {
  int t = threadIdx.x;   // 64 threads
  float v = (t < 32) ? x[t] * cw[t] : 0.f;
#pragma unroll
  for (int off = 32; off > 0; off >>= 1) v += __shfl_xor(v, off, 64);
  if (t == 0) {
    float z = v + cb[0];
    out[0] = 1.f / (1.f + expf(-z));
  }
}

extern "C" void kernel_launch(void* const* d_in, const int* in_sizes, int n_in,
                              void* d_out, int out_size, void* d_ws, size_t ws_size,
                              hipStream_t stream) {
  const float* data  = (const float*)d_in[0];
  const float* lin_w = (const float*)d_in[1];
  const float* lin_b = (const float*)d_in[2];
  const float* qkv_w = (const float*)d_in[3];
  const float* qkv_b = (const float*)d_in[4];
  const float* out_w = (const float*)d_in[5];
  const float* out_b = (const float*)d_in[6];
  const float* ln1_g = (const float*)d_in[7];
  const float* ln1_b = (const float*)d_in[8];
  const float* ff1_w = (const float*)d_in[9];
  const float* ff1_b = (const float*)d_in[10];
  const float* ff2_w = (const float*)d_in[11];
  const float* ff2_b = (const float*)d_in[12];
  const float* ln2_g = (const float*)d_in[13];
  const float* ln2_b = (const float*)d_in[14];
  const float* cls_w = (const float*)d_in[15];
  const float* cls_b = (const float*)d_in[16];

  float* ws = (float*)d_ws;
  float* X     = ws;                          // LL*32
  float* QKV   = X + (size_t)LL * 32;         // LL*96
  float* PART  = QKV + (size_t)LL * 96;       // NCHUNK*LL*NHEAD*6
  float* PART2 = PART + (size_t)NCHUNK * LL * NHEAD * 6;  // NFS*LL*32

  k_embed<<<(LL * 32 + 255) / 256, 256, 0, stream>>>(data, lin_w, lin_b, X);
  for (int l = 0; l < NLAYER; ++l) {
    k_qkv<<<(LL * 96 + 255) / 256, 256, 0, stream>>>(
        X, qkv_w + (size_t)l * 96 * 32, qkv_b + (size_t)l * 96, QKV);
    k_attn<<<dim3(5, NHEAD, NCHUNK), 256, 0, stream>>>(QKV, PART);
    k_oproj<<<(LL + 7) / 8, 256, 0, stream>>>(
        PART, X, out_w + (size_t)l * 32 * 32, out_b + (size_t)l * 32,
        ln1_g + (size_t)l * 32, ln1_b + (size_t)l * 32);
    k_ffnA<<<dim3((LL + RT - 1) / RT, NFS), 256, 0, stream>>>(
        X, ff1_w + (size_t)l * FFD * 32, ff1_b + (size_t)l * FFD,
        ff2_w + (size_t)l * 32 * FFD, PART2);
    k_ffnB<<<(LL + 7) / 8, 256, 0, stream>>>(
        X, PART2, ff2_b + (size_t)l * 32,
        ln2_g + (size_t)l * 32, ln2_b + (size_t)l * 32);
  }
  k_final<<<1, 64, 0, stream>>>(X, cls_w, cls_b, (float*)d_out);
}

// Round 4
// 729.624 us; speedup vs baseline: 3.1958x; 1.1675x over previous
//
#include <hip/hip_runtime.h>
#include <math.h>

// Problem constants
#define SEQ 4096
#define LL  4097           // sequence + CLS
#define HDIM 32
#define NHEAD 8
#define HD 4
#define FFD 2048
#define NLAYER 6
#define EPSLN 1e-5f
#define NCHUNK 32          // split-K chunks over keys 1..4096 (128 keys each)
#define QB 4               // queries per thread in k_attn
#define RT 64              // FFN row tile
#define FS 128             // FFN f-segment width
#define NFS 16             // FFD / FS

#if __has_builtin(__builtin_amdgcn_exp2f)
#define EXP2 __builtin_amdgcn_exp2f
#else
#define EXP2 exp2f
#endif

#define QSCALE 0.7213475204444817f   // 0.5 * log2(e): folds 1/sqrt(HD) and exp->exp2

__device__ __forceinline__ float dot4(float4 a, float4 b) {
  return fmaf(a.w, b.w, fmaf(a.z, b.z, fmaf(a.y, b.y, a.x * b.x)));
}

// partial record (plain sums, implicit m=0): {l, a0, a1, a2, a3}
// layout: idx = ((h*LL + q)*NCHUNK + c)*5  -> 32 records contiguous per (h,q)

// ---------------- embed: relu(feats @ lin_w.T + lin_b) + PE, CLS row = -1 ----
__global__ __launch_bounds__(256) void k_embed(const float* __restrict__ data,
    const float* __restrict__ lin_w, const float* __restrict__ lin_b,
    float* __restrict__ x) {
  int idx = blockIdx.x * 256 + threadIdx.x;   // idx = row*32 + h
  if (idx >= LL * HDIM) return;
  int row = idx >> 5, h = idx & 31;
  if (row == 0) { x[idx] = -1.0f; return; }
  int s = row - 1;
  float ts = data[s * 3 + 0];
  float f0 = data[s * 3 + 1];
  float f1 = data[s * 3 + 2];
  float lin = f0 * lin_w[h * 2 + 0] + f1 * lin_w[h * 2 + 1] + lin_b[h];
  lin = fmaxf(lin, 0.0f);
  int tsi = (int)(ts / 100.0f);
  int j = h >> 1;
  float aj = (float)(2 * j) * (float)(-0.28782313662425575);
  float divj = (float)exp((double)aj);
  float ang = (float)tsi * divj;
  float pe = (h & 1) ? cosf(ang) : sinf(ang);
  x[idx] = lin + pe;
}

// ---------------- qkv = x @ qkv_w.T + qkv_b  ([L,32]x[32,96]) ----------------
__global__ __launch_bounds__(256) void k_qkv(const float* __restrict__ x,
    const float* __restrict__ w, const float* __restrict__ b,
    float* __restrict__ qkv) {
  int idx = blockIdx.x * 256 + threadIdx.x;   // idx = row*96 + ch
  if (idx >= LL * 96) return;
  int row = idx / 96, ch = idx - row * 96;
  const float4* xr = (const float4*)(x + row * HDIM);
  const float4* wr = (const float4*)(w + ch * HDIM);
  float acc = b[ch];
#pragma unroll
  for (int k = 0; k < 8; ++k) {
    float4 xv = xr[k], wv = wr[k];
    acc = fmaf(xv.x, wv.x, acc);
    acc = fmaf(xv.y, wv.y, acc);
    acc = fmaf(xv.z, wv.z, acc);
    acc = fmaf(xv.w, wv.w, acc);
  }
  qkv[idx] = acc;
}

// ---- attention partials: flat exp2 accumulation (no max), split-K ----------
// grid (4, NHEAD, NCHUNK). q = 1 + bx*1024 + i*256 + tid covers 1..4096
// exactly. chunk c covers keys 1+c*128 .. 128+c*128 (key 0 added in k_oproj).
__global__ __launch_bounds__(256) void k_attn(const float* __restrict__ qkv,
    float* __restrict__ part) {
  int tid = threadIdx.x;
  int h = blockIdx.y;
  int c = blockIdx.z;
  int kbase = 1 + c * 128;
  __shared__ float4 kt[128];
  __shared__ float4 vt[128];
  if (tid < 128)
    kt[tid] = *(const float4*)(qkv + (size_t)(kbase + tid) * 96 + 32 + h * HD);
  else
    vt[tid - 128] =
        *(const float4*)(qkv + (size_t)(kbase + tid - 128) * 96 + 64 + h * HD);

  float4 qv[QB];
  float l[QB];
  float4 a[QB];
#pragma unroll
  for (int i = 0; i < QB; ++i) {
    int q = 1 + blockIdx.x * 1024 + i * 256 + tid;
    float4 t = *(const float4*)(qkv + (size_t)q * 96 + h * HD);
    t.x *= QSCALE; t.y *= QSCALE; t.z *= QSCALE; t.w *= QSCALE;
    qv[i] = t;
    l[i] = 0.f;
    a[i] = make_float4(0.f, 0.f, 0.f, 0.f);
  }
  __syncthreads();

  for (int j0 = 0; j0 < 128; j0 += 4) {
    float4 k0 = kt[j0], k1 = kt[j0 + 1], k2 = kt[j0 + 2], k3 = kt[j0 + 3];
    float4 v0 = vt[j0], v1 = vt[j0 + 1], v2 = vt[j0 + 2], v3 = vt[j0 + 3];
#pragma unroll
    for (int i = 0; i < QB; ++i) {
      float p0 = EXP2(dot4(qv[i], k0));
      float p1 = EXP2(dot4(qv[i], k1));
      float p2 = EXP2(dot4(qv[i], k2));
      float p3 = EXP2(dot4(qv[i], k3));
      l[i] += (p0 + p1) + (p2 + p3);
      a[i].x = fmaf(p0, v0.x, fmaf(p1, v1.x, fmaf(p2, v2.x, fmaf(p3, v3.x, a[i].x))));
      a[i].y = fmaf(p0, v0.y, fmaf(p1, v1.y, fmaf(p2, v2.y, fmaf(p3, v3.y, a[i].y))));
      a[i].z = fmaf(p0, v0.z, fmaf(p1, v1.z, fmaf(p2, v2.z, fmaf(p3, v3.z, a[i].z))));
      a[i].w = fmaf(p0, v0.w, fmaf(p1, v1.w, fmaf(p2, v2.w, fmaf(p3, v3.w, a[i].w))));
    }
  }

#pragma unroll
  for (int i = 0; i < QB; ++i) {
    int q = 1 + blockIdx.x * 1024 + i * 256 + tid;
    float* p = part + (((size_t)h * LL + q) * NCHUNK + c) * 5;
    p[0] = l[i]; p[1] = a[i].x; p[2] = a[i].y; p[3] = a[i].z; p[4] = a[i].w;
  }
}

// ---- CLS query attention (q=0, all keys incl key 0) -> record at chunk 0 ----
__global__ __launch_bounds__(256) void k_attn_cls(const float* __restrict__ qkv,
    float* __restrict__ part) {
  int h = blockIdx.x, tid = threadIdx.x;
  float4 q = *(const float4*)(qkv + h * HD);
  q.x *= QSCALE; q.y *= QSCALE; q.z *= QSCALE; q.w *= QSCALE;
  float l = 0.f;
  float4 a = make_float4(0.f, 0.f, 0.f, 0.f);
  for (int k = tid; k < LL; k += 256) {
    float4 kv = *(const float4*)(qkv + (size_t)k * 96 + 32 + h * HD);
    float4 vv = *(const float4*)(qkv + (size_t)k * 96 + 64 + h * HD);
    float p = EXP2(dot4(q, kv));
    l += p;
    a.x = fmaf(p, vv.x, a.x);
    a.y = fmaf(p, vv.y, a.y);
    a.z = fmaf(p, vv.z, a.z);
    a.w = fmaf(p, vv.w, a.w);
  }
  __shared__ float rl[256];
  __shared__ float4 ra[256];
  rl[tid] = l; ra[tid] = a;
  __syncthreads();
  for (int s = 128; s > 0; s >>= 1) {
    if (tid < s) {
      rl[tid] += rl[tid + s];
      ra[tid].x += ra[tid + s].x;
      ra[tid].y += ra[tid + s].y;
      ra[tid].z += ra[tid + s].z;
      ra[tid].w += ra[tid + s].w;
    }
    __syncthreads();
  }
  if (tid == 0) {
    float* p = part + ((size_t)h * LL + 0) * NCHUNK * 5;   // q=0, c=0
    p[0] = rl[0]; p[1] = ra[0].x; p[2] = ra[0].y; p[3] = ra[0].z; p[4] = ra[0].w;
  }
}

// ------- fused: sum split-K partials (+analytic key-0 term) + o-proj + LN1 ---
// 256 thr = 8 rows x 32 lanes. Lane ch = h*4+d.
__global__ __launch_bounds__(256) void k_oproj(const float* __restrict__ part,
    const float* __restrict__ qkv, float* __restrict__ x,
    const float* __restrict__ ow, const float* __restrict__ ob,
    const float* __restrict__ g, const float* __restrict__ bln) {
  int tid = threadIdx.x;
  int r = tid >> 5, ch = tid & 31;
  int row = blockIdx.x * 8 + r;
  __shared__ float os[8][32];
  bool ok = row < LL;
  if (ok) {
    int h = ch >> 2, d = ch & 3;
    int nch = (row == 0) ? 1 : NCHUNK;   // CLS record is a full sum at c=0
    const float* p = part + (((size_t)h * LL + row) * NCHUNK) * 5;
    float L = 0.f, A = 0.f;
    for (int c = 0; c < nch; ++c) {
      L += p[c * 5];
      A += p[c * 5 + 1 + d];
    }
    if (row != 0) {   // key 0 (CLS key) analytic term
      float4 q4 = *(const float4*)(qkv + (size_t)row * 96 + h * HD);
      float4 k04 = *(const float4*)(qkv + 32 + h * HD);
      float p0 = EXP2(QSCALE * dot4(q4, k04));
      L += p0;
      A = fmaf(p0, qkv[64 + h * HD + d], A);
    }
    os[r][ch] = A / L;
  } else {
    os[r][ch] = 0.f;
  }
  __syncthreads();
  float acc = 0.f;
#pragma unroll
  for (int k = 0; k < 32; ++k) acc = fmaf(os[r][k], ow[ch * 32 + k], acc);
  float val = ok ? (x[(size_t)row * HDIM + ch] + acc + ob[ch]) : 0.f;
  float mean = val;
#pragma unroll
  for (int off = 16; off > 0; off >>= 1) mean += __shfl_xor(mean, off, 32);
  mean *= (1.f / 32.f);
  float d2 = val - mean;
  float var = d2 * d2;
#pragma unroll
  for (int off = 16; off > 0; off >>= 1) var += __shfl_xor(var, off, 32);
  var *= (1.f / 32.f);
  float y = d2 / sqrtf(var + EPSLN) * g[ch] + bln[ch];
  if (ok) x[(size_t)row * HDIM + ch] = y;
}

// ---------------- fused FFN part A: per (row-tile, f-segment) ----------------
__global__ __launch_bounds__(256) void k_ffnA(const float* __restrict__ x,
    const float* __restrict__ w1, const float* __restrict__ b1,
    const float* __restrict__ w2, float* __restrict__ part2) {
  __shared__ float Xs[RT][33];
  __shared__ float W1t[32][132];
  __shared__ float W2t[FS][36];
  __shared__ float Fs[RT][129];
  int tid = threadIdx.x;
  int r0 = blockIdx.x * RT;
  int f0 = blockIdx.y * FS;

#pragma unroll
  for (int p = 0; p < 8; ++p) {
    int idx = p * 256 + tid;
    int r = idx >> 5, k = idx & 31;
    Xs[r][k] = (r0 + r < LL) ? x[(size_t)(r0 + r) * HDIM + k] : 0.f;
  }
#pragma unroll
  for (int p = 0; p < 16; ++p) {
    int idx = p * 256 + tid;
    int c = idx >> 5, k = idx & 31;
    W1t[k][c] = w1[(size_t)(f0 + c) * HDIM + k];
  }
#pragma unroll
  for (int p = 0; p < 16; ++p) {
    int idx = p * 256 + tid;
    int c = idx >> 7, k = idx & 127;
    W2t[k][c] = w2[(size_t)c * FFD + f0 + k];
  }
  __syncthreads();

  int rg = tid >> 4, cg = tid & 15;
  float acc[4][8];
#pragma unroll
  for (int i = 0; i < 4; ++i)
#pragma unroll
    for (int j = 0; j < 8; ++j) acc[i][j] = 0.f;
#pragma unroll
  for (int k = 0; k < 32; ++k) {
    float xv[4];
#pragma unroll
    for (int i = 0; i < 4; ++i) xv[i] = Xs[rg * 4 + i][k];
    float4 w0 = *(const float4*)&W1t[k][cg * 8];
    float4 w1v = *(const float4*)&W1t[k][cg * 8 + 4];
#pragma unroll
    for (int i = 0; i < 4; ++i) {
      acc[i][0] = fmaf(xv[i], w0.x, acc[i][0]);
      acc[i][1] = fmaf(xv[i], w0.y, acc[i][1]);
      acc[i][2] = fmaf(xv[i], w0.z, acc[i][2]);
      acc[i][3] = fmaf(xv[i], w0.w, acc[i][3]);
      acc[i][4] = fmaf(xv[i], w1v.x, acc[i][4]);
      acc[i][5] = fmaf(xv[i], w1v.y, acc[i][5]);
      acc[i][6] = fmaf(xv[i], w1v.z, acc[i][6]);
      acc[i][7] = fmaf(xv[i], w1v.w, acc[i][7]);
    }
  }
#pragma unroll
  for (int j = 0; j < 8; ++j) {
    float bb = b1[f0 + cg * 8 + j];
#pragma unroll
    for (int i = 0; i < 4; ++i)
      Fs[rg * 4 + i][cg * 8 + j] = fmaxf(acc[i][j] + bb, 0.f);
  }
  __syncthreads();

  int kq = tid >> 6, r4 = (tid >> 2) & 15, c8 = tid & 3;
  float a2[4][8];
#pragma unroll
  for (int i = 0; i < 4; ++i)
#pragma unroll
    for (int j = 0; j < 8; ++j) a2[i][j] = 0.f;
  int kbase = kq * 32;
#pragma unroll
  for (int kk = 0; kk < 32; ++kk) {
    int k = kbase + kk;
    float fv[4];
#pragma unroll
    for (int i = 0; i < 4; ++i) fv[i] = Fs[r4 * 4 + i][k];
    float4 u0 = *(const float4*)&W2t[k][c8 * 8];
    float4 u1 = *(const float4*)&W2t[k][c8 * 8 + 4];
#pragma unroll
    for (int i = 0; i < 4; ++i) {
      a2[i][0] = fmaf(fv[i], u0.x, a2[i][0]);
      a2[i][1] = fmaf(fv[i], u0.y, a2[i][1]);
      a2[i][2] = fmaf(fv[i], u0.z, a2[i][2]);
      a2[i][3] = fmaf(fv[i], u0.w, a2[i][3]);
      a2[i][4] = fmaf(fv[i], u1.x, a2[i][4]);
      a2[i][5] = fmaf(fv[i], u1.y, a2[i][5]);
      a2[i][6] = fmaf(fv[i], u1.z, a2[i][6]);
      a2[i][7] = fmaf(fv[i], u1.w, a2[i][7]);
    }
  }
  for (int q = 0; q < 4; ++q) {
    if (kq == q) {
#pragma unroll
      for (int i = 0; i < 4; ++i)
#pragma unroll
        for (int j = 0; j < 8; ++j) {
          int rr = r4 * 4 + i, cc = c8 * 8 + j;
          if (q == 0) Xs[rr][cc] = a2[i][j];
          else Xs[rr][cc] += a2[i][j];
        }
    }
    __syncthreads();
  }
#pragma unroll
  for (int p = 0; p < 8; ++p) {
    int idx = p * 256 + tid;
    int r = idx >> 5, cc = idx & 31;
    if (r0 + r < LL)
      part2[((size_t)blockIdx.y * LL + r0 + r) * HDIM + cc] = Xs[r][cc];
  }
}

// ---------------- FFN part B: combine segments + residual + LN2 --------------
__global__ __launch_bounds__(256) void k_ffnB(float* __restrict__ x,
    const float* __restrict__ part2, const float* __restrict__ b2,
    const float* __restrict__ g, const float* __restrict__ bln) {
  int tid = threadIdx.x;
  int r = tid >> 5, ch = tid & 31;
  int row = blockIdx.x * 8 + r;
  bool ok = row < LL;
  float s = 0.f;
  if (ok) {
#pragma unroll
    for (int q = 0; q < NFS; ++q)
      s += part2[((size_t)q * LL + row) * HDIM + ch];
  }
  float val = ok ? (x[(size_t)row * HDIM + ch] + s + b2[ch]) : 0.f;
  float mean = val;
#pragma unroll
  for (int off = 16; off > 0; off >>= 1) mean += __shfl_xor(mean, off, 32);
  mean *= (1.f / 32.f);
  float d = val - mean;
  float var = d * d;
#pragma unroll
  for (int off = 16; off > 0; off >>= 1) var += __shfl_xor(var, off, 32);
  var *= (1.f / 32.f);
  float y = d / sqrtf(var + EPSLN) * g[ch] + bln[ch];
  if (ok) x[(size_t)row * HDIM + ch] = y;
}

// ---------------- final: sigmoid(x[0] . cls_w + cls_b) -----------------------
__global__ void k_final(const float* __restrict__ x, const float* __restrict__ cw,
                        const float* __restrict__ cb, float* __restrict__ out) {
  int t = threadIdx.x;   // 64 threads
  float v = (t < 32) ? x[t] * cw[t] : 0.f;
#pragma unroll
  for (int off = 32; off > 0; off >>= 1) v += __shfl_xor(v, off, 64);
  if (t == 0) {
    float z = v + cb[0];
    out[0] = 1.f / (1.f + expf(-z));
  }
}

extern "C" void kernel_launch(void* const* d_in, const int* in_sizes, int n_in,
                              void* d_out, int out_size, void* d_ws, size_t ws_size,
                              hipStream_t stream) {
  const float* data  = (const float*)d_in[0];
  const float* lin_w = (const float*)d_in[1];
  const float* lin_b = (const float*)d_in[2];
  const float* qkv_w = (const float*)d_in[3];
  const float* qkv_b = (const float*)d_in[4];
  const float* out_w = (const float*)d_in[5];
  const float* out_b = (const float*)d_in[6];
  const float* ln1_g = (const float*)d_in[7];
  const float* ln1_b = (const float*)d_in[8];
  const float* ff1_w = (const float*)d_in[9];
  const float* ff1_b = (const float*)d_in[10];
  const float* ff2_w = (const float*)d_in[11];
  const float* ff2_b = (const float*)d_in[12];
  const float* ln2_g = (const float*)d_in[13];
  const float* ln2_b = (const float*)d_in[14];
  const float* cls_w = (const float*)d_in[15];
  const float* cls_b = (const float*)d_in[16];

  float* ws = (float*)d_ws;
  float* X     = ws;                          // LL*32
  float* QKV   = X + (size_t)LL * 32;         // LL*96
  float* PART  = QKV + (size_t)LL * 96;       // NHEAD*LL*NCHUNK*5 (~21 MB)
  float* PART2 = PART;                        // aliased: disjoint lifetimes

  k_embed<<<(LL * 32 + 255) / 256, 256, 0, stream>>>(data, lin_w, lin_b, X);
  for (int l = 0; l < NLAYER; ++l) {
    k_qkv<<<(LL * 96 + 255) / 256, 256, 0, stream>>>(
        X, qkv_w + (size_t)l * 96 * 32, qkv_b + (size_t)l * 96, QKV);
    k_attn<<<dim3(4, NHEAD, NCHUNK), 256, 0, stream>>>(QKV, PART);
    k_attn_cls<<<NHEAD, 256, 0, stream>>>(QKV, PART);
    k_oproj<<<(LL + 7) / 8, 256, 0, stream>>>(
        PART, QKV, X, out_w + (size_t)l * 32 * 32, out_b + (size_t)l * 32,
        ln1_g + (size_t)l * 32, ln1_b + (size_t)l * 32);
    k_ffnA<<<dim3((LL + RT - 1) / RT, NFS), 256, 0, stream>>>(
        X, ff1_w + (size_t)l * FFD * 32, ff1_b + (size_t)l * FFD,
        ff2_w + (size_t)l * 32 * FFD, PART2);
    k_ffnB<<<(LL + 7) / 8, 256, 0, stream>>>(
        X, PART2, ff2_b + (size_t)l * 32,
        ln2_g + (size_t)l * 32, ln2_b + (size_t)l * 32);
  }
  k_final<<<1, 64, 0, stream>>>(X, cls_w, cls_b, (float*)d_out);
}

// Round 5
// 678.652 us; speedup vs baseline: 3.4359x; 1.0751x over previous
//
#include <hip/hip_runtime.h>
#include <math.h>

// Problem constants
#define SEQ 4096
#define LL  4097           // sequence + CLS
#define HDIM 32
#define NHEAD 8
#define HD 4
#define FFD 2048
#define NLAYER 6
#define EPSLN 1e-5f
#define NCHUNK 32          // split-K chunks over keys 1..4096 (128 keys each)
#define QB 8               // queries per thread in k_attn
#define RT 64              // FFN row tile
#define FS 128             // FFN f-segment width
#define NFS 16             // FFD / FS

#if __has_builtin(__builtin_amdgcn_exp2f)
#define EXP2 __builtin_amdgcn_exp2f
#else
#define EXP2 exp2f
#endif

#define QSCALE 0.7213475204444817f   // 0.5 * log2(e): folds 1/sqrt(HD) and exp->exp2

__device__ __forceinline__ float dot4(float4 a, float4 b) {
  return fmaf(a.w, b.w, fmaf(a.z, b.z, fmaf(a.y, b.y, a.x * b.x)));
}

// partial sums (implicit m=0), coalesced layout:
//   LP[(c*8+h)*LL + q]  : float   denominator partial
//   AP[(c*8+h)*LL + q]  : float4  numerator partial

// ---------------- embed: relu(feats @ lin_w.T + lin_b) + PE, CLS row = -1 ----
__global__ __launch_bounds__(256) void k_embed(const float* __restrict__ data,
    const float* __restrict__ lin_w, const float* __restrict__ lin_b,
    float* __restrict__ x) {
  int idx = blockIdx.x * 256 + threadIdx.x;   // idx = row*32 + h
  if (idx >= LL * HDIM) return;
  int row = idx >> 5, h = idx & 31;
  if (row == 0) { x[idx] = -1.0f; return; }
  int s = row - 1;
  float ts = data[s * 3 + 0];
  float f0 = data[s * 3 + 1];
  float f1 = data[s * 3 + 2];
  float lin = f0 * lin_w[h * 2 + 0] + f1 * lin_w[h * 2 + 1] + lin_b[h];
  lin = fmaxf(lin, 0.0f);
  int tsi = (int)(ts / 100.0f);
  int j = h >> 1;
  float aj = (float)(2 * j) * (float)(-0.28782313662425575);
  float divj = (float)exp((double)aj);
  float ang = (float)tsi * divj;
  float pe = (h & 1) ? cosf(ang) : sinf(ang);
  x[idx] = lin + pe;
}

// -------- qkv = x @ qkv_w.T + qkv_b; thread = (row, 4-channel group) --------
__global__ __launch_bounds__(256) void k_qkv(const float* __restrict__ x,
    const float* __restrict__ w, const float* __restrict__ b,
    float* __restrict__ qkv) {
  int idx = blockIdx.x * 256 + threadIdx.x;   // idx = row*24 + c4
  if (idx >= LL * 24) return;
  int row = idx / 24, c4 = idx - row * 24;
  int ch0 = c4 * 4;
  const float4* xr = (const float4*)(x + (size_t)row * HDIM);
  float4 xv[8];
#pragma unroll
  for (int k = 0; k < 8; ++k) xv[k] = xr[k];
  float4 out;
  float* o = (float*)&out;
#pragma unroll
  for (int ch = 0; ch < 4; ++ch) {
    const float4* wr = (const float4*)(w + (size_t)(ch0 + ch) * HDIM);
    float acc = b[ch0 + ch];
#pragma unroll
    for (int k = 0; k < 8; ++k) {
      float4 wv = wr[k];
      acc = fmaf(xv[k].x, wv.x, acc);
      acc = fmaf(xv[k].y, wv.y, acc);
      acc = fmaf(xv[k].z, wv.z, acc);
      acc = fmaf(xv[k].w, wv.w, acc);
    }
    o[ch] = acc;
  }
  *(float4*)(qkv + (size_t)row * 96 + ch0) = out;
}

// ---- attention partials: flat exp2 accumulation (no max), split-K ----------
// grid (3, NHEAD, NCHUNK). bx<2: q = bx*2048 + i*256 + tid covers 0..4095.
// bx==2: q=4096 via key-parallel reduction over this chunk.
// chunk c covers keys 1+c*128 .. 128+c*128 (key 0 added analytically later).
__global__ __launch_bounds__(256) void k_attn(const float* __restrict__ qkv,
    float* __restrict__ LP, float4* __restrict__ AP) {
  int tid = threadIdx.x;
  int h = blockIdx.y;
  int c = blockIdx.z;
  int kbase = 1 + c * 128;
  size_t base = ((size_t)c * NHEAD + h) * LL;

  if (blockIdx.x == 2) {
    // ---- q=4096: 128 lanes take one key each, LDS-reduce ----
    __shared__ float rl[128];
    __shared__ float4 ra[128];
    if (tid < 128) {
      float4 q = *(const float4*)(qkv + (size_t)4096 * 96 + h * HD);
      q.x *= QSCALE; q.y *= QSCALE; q.z *= QSCALE; q.w *= QSCALE;
      float4 kv = *(const float4*)(qkv + (size_t)(kbase + tid) * 96 + 32 + h * HD);
      float4 vv = *(const float4*)(qkv + (size_t)(kbase + tid) * 96 + 64 + h * HD);
      float p = EXP2(dot4(q, kv));
      rl[tid] = p;
      ra[tid] = make_float4(p * vv.x, p * vv.y, p * vv.z, p * vv.w);
    }
    __syncthreads();
    for (int s = 64; s > 0; s >>= 1) {
      if (tid < s) {
        rl[tid] += rl[tid + s];
        ra[tid].x += ra[tid + s].x;
        ra[tid].y += ra[tid + s].y;
        ra[tid].z += ra[tid + s].z;
        ra[tid].w += ra[tid + s].w;
      }
      __syncthreads();
    }
    if (tid == 0) {
      LP[base + 4096] = rl[0];
      AP[base + 4096] = ra[0];
    }
    return;
  }

  // ---- main path: 2048 queries per block ----
  __shared__ float4 kt[128];
  __shared__ float4 vt[128];
  if (tid < 128)
    kt[tid] = *(const float4*)(qkv + (size_t)(kbase + tid) * 96 + 32 + h * HD);
  else
    vt[tid - 128] =
        *(const float4*)(qkv + (size_t)(kbase + tid - 128) * 96 + 64 + h * HD);

  float4 qv[QB];
  float l[QB];
  float4 a[QB];
  int q0 = blockIdx.x * 2048 + tid;
#pragma unroll
  for (int i = 0; i < QB; ++i) {
    int q = q0 + i * 256;
    float4 t = *(const float4*)(qkv + (size_t)q * 96 + h * HD);
    t.x *= QSCALE; t.y *= QSCALE; t.z *= QSCALE; t.w *= QSCALE;
    qv[i] = t;
    l[i] = 0.f;
    a[i] = make_float4(0.f, 0.f, 0.f, 0.f);
  }
  __syncthreads();

  for (int j0 = 0; j0 < 128; j0 += 4) {
    float4 k0 = kt[j0], k1 = kt[j0 + 1], k2 = kt[j0 + 2], k3 = kt[j0 + 3];
    float4 v0 = vt[j0], v1 = vt[j0 + 1], v2 = vt[j0 + 2], v3 = vt[j0 + 3];
#pragma unroll
    for (int i = 0; i < QB; ++i) {
      float p0 = EXP2(dot4(qv[i], k0));
      float p1 = EXP2(dot4(qv[i], k1));
      float p2 = EXP2(dot4(qv[i], k2));
      float p3 = EXP2(dot4(qv[i], k3));
      l[i] += (p0 + p1) + (p2 + p3);
      a[i].x = fmaf(p0, v0.x, fmaf(p1, v1.x, fmaf(p2, v2.x, fmaf(p3, v3.x, a[i].x))));
      a[i].y = fmaf(p0, v0.y, fmaf(p1, v1.y, fmaf(p2, v2.y, fmaf(p3, v3.y, a[i].y))));
      a[i].z = fmaf(p0, v0.z, fmaf(p1, v1.z, fmaf(p2, v2.z, fmaf(p3, v3.z, a[i].z))));
      a[i].w = fmaf(p0, v0.w, fmaf(p1, v1.w, fmaf(p2, v2.w, fmaf(p3, v3.w, a[i].w))));
    }
  }

#pragma unroll
  for (int i = 0; i < QB; ++i) {
    size_t idx = base + q0 + i * 256;
    LP[idx] = l[i];
    AP[idx] = a[i];
  }
}

// ------- fused: sum split-K partials + analytic key-0 + o-proj + LN1 --------
// 256 thr = 8 rows x 32 lanes. Lane ch = h*4+d.
__global__ __launch_bounds__(256) void k_oproj(const float* __restrict__ LP,
    const float4* __restrict__ AP, const float* __restrict__ qkv,
    float* __restrict__ x, const float* __restrict__ ow,
    const float* __restrict__ ob, const float* __restrict__ g,
    const float* __restrict__ bln) {
  int tid = threadIdx.x;
  int r = tid >> 5, ch = tid & 31;
  int row = blockIdx.x * 8 + r;
  __shared__ float os[8][32];
  bool ok = row < LL;
  if (ok) {
    int h = ch >> 2, d = ch & 3;
    float L = 0.f, A = 0.f;
#pragma unroll
    for (int c = 0; c < NCHUNK; ++c) {
      size_t idx = ((size_t)c * NHEAD + h) * LL + row;
      L += LP[idx];
      A += ((const float*)&AP[idx])[d];
    }
    // key 0 (CLS key) analytic term
    float4 q4 = *(const float4*)(qkv + (size_t)row * 96 + h * HD);
    float4 k04 = *(const float4*)(qkv + 32 + h * HD);
    float p0 = EXP2(QSCALE * dot4(q4, k04));
    L += p0;
    A = fmaf(p0, qkv[64 + h * HD + d], A);
    os[r][ch] = A / L;
  } else {
    os[r][ch] = 0.f;
  }
  __syncthreads();
  float acc = 0.f;
#pragma unroll
  for (int k = 0; k < 32; ++k) acc = fmaf(os[r][k], ow[ch * 32 + k], acc);
  float val = ok ? (x[(size_t)row * HDIM + ch] + acc + ob[ch]) : 0.f;
  float mean = val;
#pragma unroll
  for (int off = 16; off > 0; off >>= 1) mean += __shfl_xor(mean, off, 32);
  mean *= (1.f / 32.f);
  float d2 = val - mean;
  float var = d2 * d2;
#pragma unroll
  for (int off = 16; off > 0; off >>= 1) var += __shfl_xor(var, off, 32);
  var *= (1.f / 32.f);
  float y = d2 / sqrtf(var + EPSLN) * g[ch] + bln[ch];
  if (ok) x[(size_t)row * HDIM + ch] = y;
}

// ---------------- fused FFN part A: per (row-tile, f-segment) ----------------
__global__ __launch_bounds__(256) void k_ffnA(const float* __restrict__ x,
    const float* __restrict__ w1, const float* __restrict__ b1,
    const float* __restrict__ w2, float* __restrict__ part2) {
  __shared__ float Xs[RT][33];
  __shared__ float W1t[32][132];
  __shared__ float W2t[FS][36];
  __shared__ float Fs[RT][129];
  int tid = threadIdx.x;
  int r0 = blockIdx.x * RT;
  int f0 = blockIdx.y * FS;

#pragma unroll
  for (int p = 0; p < 8; ++p) {
    int idx = p * 256 + tid;
    int r = idx >> 5, k = idx & 31;
    Xs[r][k] = (r0 + r < LL) ? x[(size_t)(r0 + r) * HDIM + k] : 0.f;
  }
#pragma unroll
  for (int p = 0; p < 16; ++p) {
    int idx = p * 256 + tid;
    int c = idx >> 5, k = idx & 31;
    W1t[k][c] = w1[(size_t)(f0 + c) * HDIM + k];
  }
#pragma unroll
  for (int p = 0; p < 16; ++p) {
    int idx = p * 256 + tid;
    int c = idx >> 7, k = idx & 127;
    W2t[k][c] = w2[(size_t)c * FFD + f0 + k];
  }
  __syncthreads();

  int rg = tid >> 4, cg = tid & 15;
  float acc[4][8];
#pragma unroll
  for (int i = 0; i < 4; ++i)
#pragma unroll
    for (int j = 0; j < 8; ++j) acc[i][j] = 0.f;
#pragma unroll
  for (int k = 0; k < 32; ++k) {
    float xv[4];
#pragma unroll
    for (int i = 0; i < 4; ++i) xv[i] = Xs[rg * 4 + i][k];
    float4 w0 = *(const float4*)&W1t[k][cg * 8];
    float4 w1v = *(const float4*)&W1t[k][cg * 8 + 4];
#pragma unroll
    for (int i = 0; i < 4; ++i) {
      acc[i][0] = fmaf(xv[i], w0.x, acc[i][0]);
      acc[i][1] = fmaf(xv[i], w0.y, acc[i][1]);
      acc[i][2] = fmaf(xv[i], w0.z, acc[i][2]);
      acc[i][3] = fmaf(xv[i], w0.w, acc[i][3]);
      acc[i][4] = fmaf(xv[i], w1v.x, acc[i][4]);
      acc[i][5] = fmaf(xv[i], w1v.y, acc[i][5]);
      acc[i][6] = fmaf(xv[i], w1v.z, acc[i][6]);
      acc[i][7] = fmaf(xv[i], w1v.w, acc[i][7]);
    }
  }
#pragma unroll
  for (int j = 0; j < 8; ++j) {
    float bb = b1[f0 + cg * 8 + j];
#pragma unroll
    for (int i = 0; i < 4; ++i)
      Fs[rg * 4 + i][cg * 8 + j] = fmaxf(acc[i][j] + bb, 0.f);
  }
  __syncthreads();

  int kq = tid >> 6, r4 = (tid >> 2) & 15, c8 = tid & 3;
  float a2[4][8];
#pragma unroll
  for (int i = 0; i < 4; ++i)
#pragma unroll
    for (int j = 0; j < 8; ++j) a2[i][j] = 0.f;
  int kbase = kq * 32;
#pragma unroll
  for (int kk = 0; kk < 32; ++kk) {
    int k = kbase + kk;
    float fv[4];
#pragma unroll
    for (int i = 0; i < 4; ++i) fv[i] = Fs[r4 * 4 + i][k];
    float4 u0 = *(const float4*)&W2t[k][c8 * 8];
    float4 u1 = *(const float4*)&W2t[k][c8 * 8 + 4];
#pragma unroll
    for (int i = 0; i < 4; ++i) {
      a2[i][0] = fmaf(fv[i], u0.x, a2[i][0]);
      a2[i][1] = fmaf(fv[i], u0.y, a2[i][1]);
      a2[i][2] = fmaf(fv[i], u0.z, a2[i][2]);
      a2[i][3] = fmaf(fv[i], u0.w, a2[i][3]);
      a2[i][4] = fmaf(fv[i], u1.x, a2[i][4]);
      a2[i][5] = fmaf(fv[i], u1.y, a2[i][5]);
      a2[i][6] = fmaf(fv[i], u1.z, a2[i][6]);
      a2[i][7] = fmaf(fv[i], u1.w, a2[i][7]);
    }
  }
  for (int q = 0; q < 4; ++q) {
    if (kq == q) {
#pragma unroll
      for (int i = 0; i < 4; ++i)
#pragma unroll
        for (int j = 0; j < 8; ++j) {
          int rr = r4 * 4 + i, cc = c8 * 8 + j;
          if (q == 0) Xs[rr][cc] = a2[i][j];
          else Xs[rr][cc] += a2[i][j];
        }
    }
    __syncthreads();
  }
#pragma unroll
  for (int p = 0; p < 8; ++p) {
    int idx = p * 256 + tid;
    int r = idx >> 5, cc = idx & 31;
    if (r0 + r < LL)
      part2[((size_t)blockIdx.y * LL + r0 + r) * HDIM + cc] = Xs[r][cc];
  }
}

// ---------------- FFN part B: combine segments + residual + LN2 --------------
__global__ __launch_bounds__(256) void k_ffnB(float* __restrict__ x,
    const float* __restrict__ part2, const float* __restrict__ b2,
    const float* __restrict__ g, const float* __restrict__ bln) {
  int tid = threadIdx.x;
  int r = tid >> 5, ch = tid & 31;
  int row = blockIdx.x * 8 + r;
  bool ok = row < LL;
  float s = 0.f;
  if (ok) {
#pragma unroll
    for (int q = 0; q < NFS; ++q)
      s += part2[((size_t)q * LL + row) * HDIM + ch];
  }
  float val = ok ? (x[(size_t)row * HDIM + ch] + s + b2[ch]) : 0.f;
  float mean = val;
#pragma unroll
  for (int off = 16; off > 0; off >>= 1) mean += __shfl_xor(mean, off, 32);
  mean *= (1.f / 32.f);
  float d = val - mean;
  float var = d * d;
#pragma unroll
  for (int off = 16; off > 0; off >>= 1) var += __shfl_xor(var, off, 32);
  var *= (1.f / 32.f);
  float y = d / sqrtf(var + EPSLN) * g[ch] + bln[ch];
  if (ok) x[(size_t)row * HDIM + ch] = y;
}

// ---------------- final: sigmoid(x[0] . cls_w + cls_b) -----------------------
__global__ void k_final(const float* __restrict__ x, const float* __restrict__ cw,
                        const float* __restrict__ cb, float* __restrict__ out) {
  int t = threadIdx.x;   // 64 threads
  float v = (t < 32) ? x[t] * cw[t] : 0.f;
#pragma unroll
  for (int off = 32; off > 0; off >>= 1) v += __shfl_xor(v, off, 64);
  if (t == 0) {
    float z = v + cb[0];
    out[0] = 1.f / (1.f + expf(-z));
  }
}

extern "C" void kernel_launch(void* const* d_in, const int* in_sizes, int n_in,
                              void* d_out, int out_size, void* d_ws, size_t ws_size,
                              hipStream_t stream) {
  const float* data  = (const float*)d_in[0];
  const float* lin_w = (const float*)d_in[1];
  const float* lin_b = (const float*)d_in[2];
  const float* qkv_w = (const float*)d_in[3];
  const float* qkv_b = (const float*)d_in[4];
  const float* out_w = (const float*)d_in[5];
  const float* out_b = (const float*)d_in[6];
  const float* ln1_g = (const float*)d_in[7];
  const float* ln1_b = (const float*)d_in[8];
  const float* ff1_w = (const float*)d_in[9];
  const float* ff1_b = (const float*)d_in[10];
  const float* ff2_w = (const float*)d_in[11];
  const float* ff2_b = (const float*)d_in[12];
  const float* ln2_g = (const float*)d_in[13];
  const float* ln2_b = (const float*)d_in[14];
  const float* cls_w = (const float*)d_in[15];
  const float* cls_b = (const float*)d_in[16];

  float* ws = (float*)d_ws;
  float*  X   = ws;                            // LL*32
  float*  QKV = X + (size_t)LL * 32;           // LL*96
  float4* AP  = (float4*)(QKV + (size_t)LL * 96);  // NCHUNK*NHEAD*LL float4 (16B-aligned)
  float*  LP  = (float*)(AP + (size_t)NCHUNK * NHEAD * LL);  // NCHUNK*NHEAD*LL
  float*  PART2 = (float*)AP;                  // aliased: disjoint lifetimes

  k_embed<<<(LL * 32 + 255) / 256, 256, 0, stream>>>(data, lin_w, lin_b, X);
  for (int l = 0; l < NLAYER; ++l) {
    k_qkv<<<(LL * 24 + 255) / 256, 256, 0, stream>>>(
        X, qkv_w + (size_t)l * 96 * 32, qkv_b + (size_t)l * 96, QKV);
    k_attn<<<dim3(3, NHEAD, NCHUNK), 256, 0, stream>>>(QKV, LP, AP);
    k_oproj<<<(LL + 7) / 8, 256, 0, stream>>>(
        LP, AP, QKV, X, out_w + (size_t)l * 32 * 32, out_b + (size_t)l * 32,
        ln1_g + (size_t)l * 32, ln1_b + (size_t)l * 32);
    k_ffnA<<<dim3((LL + RT - 1) / RT, NFS), 256, 0, stream>>>(
        X, ff1_w + (size_t)l * FFD * 32, ff1_b + (size_t)l * FFD,
        ff2_w + (size_t)l * 32 * FFD, PART2);
    k_ffnB<<<(LL + 7) / 8, 256, 0, stream>>>(
        X, PART2, ff2_b + (size_t)l * 32,
        ln2_g + (size_t)l * 32, ln2_b + (size_t)l * 32);
  }
  k_final<<<1, 64, 0, stream>>>(X, cls_w, cls_b, (float*)d_out);
}

// Round 6
// 644.432 us; speedup vs baseline: 3.6183x; 1.0531x over previous
//
#include <hip/hip_runtime.h>
#include <math.h>

// Problem constants
#define SEQ 4096
#define LL  4097           // sequence + CLS
#define HDIM 32
#define NHEAD 8
#define HD 4
#define FFD 2048
#define NLAYER 6
#define EPSLN 1e-5f
#define NCHUNK 32          // split-K chunks over keys 1..4096 (128 keys each)
#define QB 2               // queries per thread in k_attn
#define RT 64              // FFN row tile
#define FS 128             // FFN f-segment width
#define NFS 16             // FFD / FS

#if __has_builtin(__builtin_amdgcn_exp2f)
#define EXP2 __builtin_amdgcn_exp2f
#else
#define EXP2 exp2f
#endif

#define QSCALE 0.7213475204444817f   // 0.5 * log2(e): folds 1/sqrt(HD) and exp->exp2

__device__ __forceinline__ float dot4(float4 a, float4 b) {
  return fmaf(a.w, b.w, fmaf(a.z, b.z, fmaf(a.y, b.y, a.x * b.x)));
}

// partial sums (implicit m=0), coalesced layout:
//   LP[(c*8+h)*LL + q]  : float   denominator partial
//   AP[(c*8+h)*LL + q]  : float4  numerator partial

// -------- embed (relu(lin)+PE, CLS=-1) fused with layer-0 qkv ---------------
// 256 thr = 8 rows x 32 ch.
__global__ __launch_bounds__(256) void k_embed_qkv(const float* __restrict__ data,
    const float* __restrict__ lin_w, const float* __restrict__ lin_b,
    float* __restrict__ x, const float* __restrict__ qw,
    const float* __restrict__ qb, float* __restrict__ qkv) {
  __shared__ float xs[8][33];
  int tid = threadIdx.x;
  int r = tid >> 5, ch = tid & 31;
  int row = blockIdx.x * 8 + r;
  bool ok = row < LL;
  float val = 0.f;
  if (ok) {
    if (row == 0) {
      val = -1.0f;
    } else {
      int s = row - 1;
      float ts = data[s * 3 + 0];
      float f0 = data[s * 3 + 1];
      float f1 = data[s * 3 + 2];
      float lin = f0 * lin_w[ch * 2 + 0] + f1 * lin_w[ch * 2 + 1] + lin_b[ch];
      lin = fmaxf(lin, 0.0f);
      int tsi = (int)(ts / 100.0f);
      int j = ch >> 1;
      float aj = (float)(2 * j) * (float)(-0.28782313662425575);
      float divj = (float)exp((double)aj);
      float ang = (float)tsi * divj;
      float pe = (ch & 1) ? cosf(ang) : sinf(ang);
      val = lin + pe;
    }
    x[(size_t)row * HDIM + ch] = val;
  }
  xs[r][ch] = val;
  __syncthreads();
  if (!ok) return;
#pragma unroll
  for (int t3 = 0; t3 < 3; ++t3) {
    int cc = t3 * 32 + ch;
    const float4* wr = (const float4*)(qw + (size_t)cc * HDIM);
    float acc = qb[cc];
#pragma unroll
    for (int k = 0; k < 8; ++k) {
      float4 wv = wr[k];
      acc = fmaf(xs[r][4 * k + 0], wv.x, acc);
      acc = fmaf(xs[r][4 * k + 1], wv.y, acc);
      acc = fmaf(xs[r][4 * k + 2], wv.z, acc);
      acc = fmaf(xs[r][4 * k + 3], wv.w, acc);
    }
    qkv[(size_t)row * 96 + cc] = acc;
  }
}

// ---- attention partials: flat exp2 accumulation (no max), split-K ----------
// grid (9, NHEAD, NCHUNK). bx<8: q = bx*512 + i*256 + tid covers 0..4095
// (CLS q=0 included; its key-0 term added analytically in oproj like all rows).
// bx==8: q=4096 via key-parallel reduction over this chunk.
// chunk c covers keys 1+c*128 .. 128+c*128 (key 0 handled in oproj).
__global__ __launch_bounds__(256, 6) void k_attn(const float* __restrict__ qkv,
    float* __restrict__ LP, float4* __restrict__ AP) {
  int tid = threadIdx.x;
  int h = blockIdx.y;
  int c = blockIdx.z;
  int kbase = 1 + c * 128;
  size_t base = ((size_t)c * NHEAD + h) * LL;

  if (blockIdx.x == 8) {
    // ---- q=4096: 128 lanes take one key each, LDS-reduce ----
    __shared__ float rl[128];
    __shared__ float4 ra[128];
    if (tid < 128) {
      float4 q = *(const float4*)(qkv + (size_t)4096 * 96 + h * HD);
      q.x *= QSCALE; q.y *= QSCALE; q.z *= QSCALE; q.w *= QSCALE;
      float4 kv = *(const float4*)(qkv + (size_t)(kbase + tid) * 96 + 32 + h * HD);
      float4 vv = *(const float4*)(qkv + (size_t)(kbase + tid) * 96 + 64 + h * HD);
      float p = EXP2(dot4(q, kv));
      rl[tid] = p;
      ra[tid] = make_float4(p * vv.x, p * vv.y, p * vv.z, p * vv.w);
    }
    __syncthreads();
    for (int s = 64; s > 0; s >>= 1) {
      if (tid < s) {
        rl[tid] += rl[tid + s];
        ra[tid].x += ra[tid + s].x;
        ra[tid].y += ra[tid + s].y;
        ra[tid].z += ra[tid + s].z;
        ra[tid].w += ra[tid + s].w;
      }
      __syncthreads();
    }
    if (tid == 0) {
      LP[base + 4096] = rl[0];
      AP[base + 4096] = ra[0];
    }
    return;
  }

  // ---- main path: 512 queries per block ----
  __shared__ float4 kt[128];
  __shared__ float4 vt[128];
  if (tid < 128)
    kt[tid] = *(const float4*)(qkv + (size_t)(kbase + tid) * 96 + 32 + h * HD);
  else
    vt[tid - 128] =
        *(const float4*)(qkv + (size_t)(kbase + tid - 128) * 96 + 64 + h * HD);

  float4 qv[QB];
  float l[QB];
  float4 a[QB];
  int q0 = blockIdx.x * 512 + tid;
#pragma unroll
  for (int i = 0; i < QB; ++i) {
    int q = q0 + i * 256;
    float4 t = *(const float4*)(qkv + (size_t)q * 96 + h * HD);
    t.x *= QSCALE; t.y *= QSCALE; t.z *= QSCALE; t.w *= QSCALE;
    qv[i] = t;
    l[i] = 0.f;
    a[i] = make_float4(0.f, 0.f, 0.f, 0.f);
  }
  __syncthreads();

  for (int j0 = 0; j0 < 128; j0 += 4) {
    float4 k0 = kt[j0], k1 = kt[j0 + 1], k2 = kt[j0 + 2], k3 = kt[j0 + 3];
    float4 v0 = vt[j0], v1 = vt[j0 + 1], v2 = vt[j0 + 2], v3 = vt[j0 + 3];
#pragma unroll
    for (int i = 0; i < QB; ++i) {
      float p0 = EXP2(dot4(qv[i], k0));
      float p1 = EXP2(dot4(qv[i], k1));
      float p2 = EXP2(dot4(qv[i], k2));
      float p3 = EXP2(dot4(qv[i], k3));
      l[i] += (p0 + p1) + (p2 + p3);
      a[i].x = fmaf(p0, v0.x, fmaf(p1, v1.x, fmaf(p2, v2.x, fmaf(p3, v3.x, a[i].x))));
      a[i].y = fmaf(p0, v0.y, fmaf(p1, v1.y, fmaf(p2, v2.y, fmaf(p3, v3.y, a[i].y))));
      a[i].z = fmaf(p0, v0.z, fmaf(p1, v1.z, fmaf(p2, v2.z, fmaf(p3, v3.z, a[i].z))));
      a[i].w = fmaf(p0, v0.w, fmaf(p1, v1.w, fmaf(p2, v2.w, fmaf(p3, v3.w, a[i].w))));
    }
  }

#pragma unroll
  for (int i = 0; i < QB; ++i) {
    size_t idx = base + q0 + i * 256;
    LP[idx] = l[i];
    AP[idx] = a[i];
  }
}

// ------- fused: sum split-K partials + analytic key-0 + o-proj + LN1 --------
// 256 thr = 8 rows x 32 lanes. Lane ch = h*4+d.
__global__ __launch_bounds__(256) void k_oproj(const float* __restrict__ LP,
    const float4* __restrict__ AP, const float* __restrict__ qkv,
    float* __restrict__ x, const float* __restrict__ ow,
    const float* __restrict__ ob, const float* __restrict__ g,
    const float* __restrict__ bln) {
  int tid = threadIdx.x;
  int r = tid >> 5, ch = tid & 31;
  int row = blockIdx.x * 8 + r;
  __shared__ float os[8][32];
  bool ok = row < LL;
  if (ok) {
    int h = ch >> 2, d = ch & 3;
    float L = 0.f, A = 0.f;
#pragma unroll
    for (int c = 0; c < NCHUNK; ++c) {
      size_t idx = ((size_t)c * NHEAD + h) * LL + row;
      L += LP[idx];
      A += ((const float*)&AP[idx])[d];
    }
    // key 0 (CLS key) analytic term
    float4 q4 = *(const float4*)(qkv + (size_t)row * 96 + h * HD);
    float4 k04 = *(const float4*)(qkv + 32 + h * HD);
    float p0 = EXP2(QSCALE * dot4(q4, k04));
    L += p0;
    A = fmaf(p0, qkv[64 + h * HD + d], A);
    os[r][ch] = A / L;
  } else {
    os[r][ch] = 0.f;
  }
  __syncthreads();
  float acc = 0.f;
#pragma unroll
  for (int k = 0; k < 32; ++k) acc = fmaf(os[r][k], ow[ch * 32 + k], acc);
  float val = ok ? (x[(size_t)row * HDIM + ch] + acc + ob[ch]) : 0.f;
  float mean = val;
#pragma unroll
  for (int off = 16; off > 0; off >>= 1) mean += __shfl_xor(mean, off, 32);
  mean *= (1.f / 32.f);
  float d2 = val - mean;
  float var = d2 * d2;
#pragma unroll
  for (int off = 16; off > 0; off >>= 1) var += __shfl_xor(var, off, 32);
  var *= (1.f / 32.f);
  float y = d2 / sqrtf(var + EPSLN) * g[ch] + bln[ch];
  if (ok) x[(size_t)row * HDIM + ch] = y;
}

// ---------------- fused FFN part A: per (row-tile, f-segment) ----------------
__global__ __launch_bounds__(256) void k_ffnA(const float* __restrict__ x,
    const float* __restrict__ w1, const float* __restrict__ b1,
    const float* __restrict__ w2, float* __restrict__ part2) {
  __shared__ float Xs[RT][33];
  __shared__ float W1t[32][132];
  __shared__ float W2t[FS][36];
  __shared__ float Fs[RT][129];
  int tid = threadIdx.x;
  int r0 = blockIdx.x * RT;
  int f0 = blockIdx.y * FS;

#pragma unroll
  for (int p = 0; p < 8; ++p) {
    int idx = p * 256 + tid;
    int r = idx >> 5, k = idx & 31;
    Xs[r][k] = (r0 + r < LL) ? x[(size_t)(r0 + r) * HDIM + k] : 0.f;
  }
#pragma unroll
  for (int p = 0; p < 16; ++p) {
    int idx = p * 256 + tid;
    int c = idx >> 5, k = idx & 31;
    W1t[k][c] = w1[(size_t)(f0 + c) * HDIM + k];
  }
#pragma unroll
  for (int p = 0; p < 16; ++p) {
    int idx = p * 256 + tid;
    int c = idx >> 7, k = idx & 127;
    W2t[k][c] = w2[(size_t)c * FFD + f0 + k];
  }
  __syncthreads();

  int rg = tid >> 4, cg = tid & 15;
  float acc[4][8];
#pragma unroll
  for (int i = 0; i < 4; ++i)
#pragma unroll
    for (int j = 0; j < 8; ++j) acc[i][j] = 0.f;
#pragma unroll
  for (int k = 0; k < 32; ++k) {
    float xv[4];
#pragma unroll
    for (int i = 0; i < 4; ++i) xv[i] = Xs[rg * 4 + i][k];
    float4 w0 = *(const float4*)&W1t[k][cg * 8];
    float4 w1v = *(const float4*)&W1t[k][cg * 8 + 4];
#pragma unroll
    for (int i = 0; i < 4; ++i) {
      acc[i][0] = fmaf(xv[i], w0.x, acc[i][0]);
      acc[i][1] = fmaf(xv[i], w0.y, acc[i][1]);
      acc[i][2] = fmaf(xv[i], w0.z, acc[i][2]);
      acc[i][3] = fmaf(xv[i], w0.w, acc[i][3]);
      acc[i][4] = fmaf(xv[i], w1v.x, acc[i][4]);
      acc[i][5] = fmaf(xv[i], w1v.y, acc[i][5]);
      acc[i][6] = fmaf(xv[i], w1v.z, acc[i][6]);
      acc[i][7] = fmaf(xv[i], w1v.w, acc[i][7]);
    }
  }
#pragma unroll
  for (int j = 0; j < 8; ++j) {
    float bb = b1[f0 + cg * 8 + j];
#pragma unroll
    for (int i = 0; i < 4; ++i)
      Fs[rg * 4 + i][cg * 8 + j] = fmaxf(acc[i][j] + bb, 0.f);
  }
  __syncthreads();

  int kq = tid >> 6, r4 = (tid >> 2) & 15, c8 = tid & 3;
  float a2[4][8];
#pragma unroll
  for (int i = 0; i < 4; ++i)
#pragma unroll
    for (int j = 0; j < 8; ++j) a2[i][j] = 0.f;
  int kbase = kq * 32;
#pragma unroll
  for (int kk = 0; kk < 32; ++kk) {
    int k = kbase + kk;
    float fv[4];
#pragma unroll
    for (int i = 0; i < 4; ++i) fv[i] = Fs[r4 * 4 + i][k];
    float4 u0 = *(const float4*)&W2t[k][c8 * 8];
    float4 u1 = *(const float4*)&W2t[k][c8 * 8 + 4];
#pragma unroll
    for (int i = 0; i < 4; ++i) {
      a2[i][0] = fmaf(fv[i], u0.x, a2[i][0]);
      a2[i][1] = fmaf(fv[i], u0.y, a2[i][1]);
      a2[i][2] = fmaf(fv[i], u0.z, a2[i][2]);
      a2[i][3] = fmaf(fv[i], u0.w, a2[i][3]);
      a2[i][4] = fmaf(fv[i], u1.x, a2[i][4]);
      a2[i][5] = fmaf(fv[i], u1.y, a2[i][5]);
      a2[i][6] = fmaf(fv[i], u1.z, a2[i][6]);
      a2[i][7] = fmaf(fv[i], u1.w, a2[i][7]);
    }
  }
  for (int q = 0; q < 4; ++q) {
    if (kq == q) {
#pragma unroll
      for (int i = 0; i < 4; ++i)
#pragma unroll
        for (int j = 0; j < 8; ++j) {
          int rr = r4 * 4 + i, cc = c8 * 8 + j;
          if (q == 0) Xs[rr][cc] = a2[i][j];
          else Xs[rr][cc] += a2[i][j];
        }
    }
    __syncthreads();
  }
#pragma unroll
  for (int p = 0; p < 8; ++p) {
    int idx = p * 256 + tid;
    int r = idx >> 5, cc = idx & 31;
    if (r0 + r < LL)
      part2[((size_t)blockIdx.y * LL + r0 + r) * HDIM + cc] = Xs[r][cc];
  }
}

// ------ FFN part B: combine segments + residual + LN2, fused next-layer qkv --
__global__ __launch_bounds__(256) void k_ffnB_qkv(float* __restrict__ x,
    const float* __restrict__ part2, const float* __restrict__ b2,
    const float* __restrict__ g, const float* __restrict__ bln,
    const float* __restrict__ qw, const float* __restrict__ qb,
    float* __restrict__ qkv, int do_qkv) {
  __shared__ float xs[8][33];
  int tid = threadIdx.x;
  int r = tid >> 5, ch = tid & 31;
  int row = blockIdx.x * 8 + r;
  bool ok = row < LL;
  float s = 0.f;
  if (ok) {
#pragma unroll
    for (int q = 0; q < NFS; ++q)
      s += part2[((size_t)q * LL + row) * HDIM + ch];
  }
  float val = ok ? (x[(size_t)row * HDIM + ch] + s + b2[ch]) : 0.f;
  float mean = val;
#pragma unroll
  for (int off = 16; off > 0; off >>= 1) mean += __shfl_xor(mean, off, 32);
  mean *= (1.f / 32.f);
  float d = val - mean;
  float var = d * d;
#pragma unroll
  for (int off = 16; off > 0; off >>= 1) var += __shfl_xor(var, off, 32);
  var *= (1.f / 32.f);
  float y = d / sqrtf(var + EPSLN) * g[ch] + bln[ch];
  if (ok) x[(size_t)row * HDIM + ch] = y;
  xs[r][ch] = ok ? y : 0.f;
  __syncthreads();
  if (!do_qkv || !ok) return;
#pragma unroll
  for (int t3 = 0; t3 < 3; ++t3) {
    int cc = t3 * 32 + ch;
    const float4* wr = (const float4*)(qw + (size_t)cc * HDIM);
    float acc = qb[cc];
#pragma unroll
    for (int k = 0; k < 8; ++k) {
      float4 wv = wr[k];
      acc = fmaf(xs[r][4 * k + 0], wv.x, acc);
      acc = fmaf(xs[r][4 * k + 1], wv.y, acc);
      acc = fmaf(xs[r][4 * k + 2], wv.z, acc);
      acc = fmaf(xs[r][4 * k + 3], wv.w, acc);
    }
    qkv[(size_t)row * 96 + cc] = acc;
  }
}

// ---------------- final: sigmoid(x[0] . cls_w + cls_b) -----------------------
__global__ void k_final(const float* __restrict__ x, const float* __restrict__ cw,
                        const float* __restrict__ cb, float* __restrict__ out) {
  int t = threadIdx.x;   // 64 threads
  float v = (t < 32) ? x[t] * cw[t] : 0.f;
#pragma unroll
  for (int off = 32; off > 0; off >>= 1) v += __shfl_xor(v, off, 64);
  if (t == 0) {
    float z = v + cb[0];
    out[0] = 1.f / (1.f + expf(-z));
  }
}

extern "C" void kernel_launch(void* const* d_in, const int* in_sizes, int n_in,
                              void* d_out, int out_size, void* d_ws, size_t ws_size,
                              hipStream_t stream) {
  const float* data  = (const float*)d_in[0];
  const float* lin_w = (const float*)d_in[1];
  const float* lin_b = (const float*)d_in[2];
  const float* qkv_w = (const float*)d_in[3];
  const float* qkv_b = (const float*)d_in[4];
  const float* out_w = (const float*)d_in[5];
  const float* out_b = (const float*)d_in[6];
  const float* ln1_g = (const float*)d_in[7];
  const float* ln1_b = (const float*)d_in[8];
  const float* ff1_w = (const float*)d_in[9];
  const float* ff1_b = (const float*)d_in[10];
  const float* ff2_w = (const float*)d_in[11];
  const float* ff2_b = (const float*)d_in[12];
  const float* ln2_g = (const float*)d_in[13];
  const float* ln2_b = (const float*)d_in[14];
  const float* cls_w = (const float*)d_in[15];
  const float* cls_b = (const float*)d_in[16];

  float* ws = (float*)d_ws;
  float*  X   = ws;                            // LL*32
  float*  QKV = X + (size_t)LL * 32;           // LL*96
  float4* AP  = (float4*)(QKV + (size_t)LL * 96);  // NCHUNK*NHEAD*LL float4
  float*  LP  = (float*)(AP + (size_t)NCHUNK * NHEAD * LL);  // NCHUNK*NHEAD*LL
  float*  PART2 = (float*)AP;                  // aliased: disjoint lifetimes

  const int NROWB = (LL + 7) / 8;              // 513

  k_embed_qkv<<<NROWB, 256, 0, stream>>>(data, lin_w, lin_b, X,
                                         qkv_w, qkv_b, QKV);
  for (int l = 0; l < NLAYER; ++l) {
    k_attn<<<dim3(9, NHEAD, NCHUNK), 256, 0, stream>>>(QKV, LP, AP);
    k_oproj<<<NROWB, 256, 0, stream>>>(
        LP, AP, QKV, X, out_w + (size_t)l * 32 * 32, out_b + (size_t)l * 32,
        ln1_g + (size_t)l * 32, ln1_b + (size_t)l * 32);
    k_ffnA<<<dim3((LL + RT - 1) / RT, NFS), 256, 0, stream>>>(
        X, ff1_w + (size_t)l * FFD * 32, ff1_b + (size_t)l * FFD,
        ff2_w + (size_t)l * 32 * FFD, PART2);
    int nl = l + 1;
    int do_qkv = (nl < NLAYER) ? 1 : 0;
    const float* qw = qkv_w + (size_t)(do_qkv ? nl : 0) * 96 * 32;
    const float* qb = qkv_b + (size_t)(do_qkv ? nl : 0) * 96;
    k_ffnB_qkv<<<NROWB, 256, 0, stream>>>(
        X, PART2, ff2_b + (size_t)l * 32,
        ln2_g + (size_t)l * 32, ln2_b + (size_t)l * 32,
        qw, qb, QKV, do_qkv);
  }
  k_final<<<1, 64, 0, stream>>>(X, cls_w, cls_b, (float*)d_out);
}

// Round 7
// 640.928 us; speedup vs baseline: 3.6381x; 1.0055x over previous
//
#include <hip/hip_runtime.h>
#include <math.h>

// Problem constants
#define SEQ 4096
#define LL  4097           // sequence + CLS
#define HDIM 32
#define NHEAD 8
#define HD 4
#define FFD 2048
#define NLAYER 6
#define EPSLN 1e-5f
#define NCHUNK 16          // split-K chunks over keys 1..4096 (256 keys each)
#define QB 2               // queries per thread in k_attn
#define RT 64              // FFN row tile
#define FS 128             // FFN f-segment width
#define NFS 16             // FFD / FS

#if __has_builtin(__builtin_amdgcn_exp2f)
#define EXP2 __builtin_amdgcn_exp2f
#else
#define EXP2 exp2f
#endif

#define QSCALE 0.7213475204444817f   // 0.5 * log2(e): folds 1/sqrt(HD) and exp->exp2

typedef float v2f __attribute__((ext_vector_type(2)));
#define FMA2(a, b, c) __builtin_elementwise_fma((a), (b), (c))

__device__ __forceinline__ float dot4(float4 a, float4 b) {
  return fmaf(a.w, b.w, fmaf(a.z, b.z, fmaf(a.y, b.y, a.x * b.x)));
}

// partial sums (implicit m=0), coalesced layout:
//   LP[(c*8+h)*LL + q]  : float   denominator partial
//   AP[(c*8+h)*LL + q]  : float4  numerator partial

// -------- embed (relu(lin)+PE, CLS=-1) fused with layer-0 qkv ---------------
__global__ __launch_bounds__(256) void k_embed_qkv(const float* __restrict__ data,
    const float* __restrict__ lin_w, const float* __restrict__ lin_b,
    float* __restrict__ x, const float* __restrict__ qw,
    const float* __restrict__ qb, float* __restrict__ qkv) {
  __shared__ float xs[8][33];
  int tid = threadIdx.x;
  int r = tid >> 5, ch = tid & 31;
  int row = blockIdx.x * 8 + r;
  bool ok = row < LL;
  float val = 0.f;
  if (ok) {
    if (row == 0) {
      val = -1.0f;
    } else {
      int s = row - 1;
      float ts = data[s * 3 + 0];
      float f0 = data[s * 3 + 1];
      float f1 = data[s * 3 + 2];
      float lin = f0 * lin_w[ch * 2 + 0] + f1 * lin_w[ch * 2 + 1] + lin_b[ch];
      lin = fmaxf(lin, 0.0f);
      int tsi = (int)(ts / 100.0f);
      int j = ch >> 1;
      float aj = (float)(2 * j) * (float)(-0.28782313662425575);
      float divj = (float)exp((double)aj);
      float ang = (float)tsi * divj;
      float pe = (ch & 1) ? cosf(ang) : sinf(ang);
      val = lin + pe;
    }
    x[(size_t)row * HDIM + ch] = val;
  }
  xs[r][ch] = val;
  __syncthreads();
  if (!ok) return;
#pragma unroll
  for (int t3 = 0; t3 < 3; ++t3) {
    int cc = t3 * 32 + ch;
    const float4* wr = (const float4*)(qw + (size_t)cc * HDIM);
    float acc = qb[cc];
#pragma unroll
    for (int k = 0; k < 8; ++k) {
      float4 wv = wr[k];
      acc = fmaf(xs[r][4 * k + 0], wv.x, acc);
      acc = fmaf(xs[r][4 * k + 1], wv.y, acc);
      acc = fmaf(xs[r][4 * k + 2], wv.z, acc);
      acc = fmaf(xs[r][4 * k + 3], wv.w, acc);
    }
    qkv[(size_t)row * 96 + cc] = acc;
  }
}

// ---- attention partials: flat exp2, split-K, packed-fp32 key pairs ---------
// grid (9, NHEAD, NCHUNK). bx<8: q = bx*512 + i*256 + tid covers 0..4095
// (CLS q=0 included). bx==8: q=4096 via key-parallel reduction.
// chunk c covers keys 1+c*256 .. 256+c*256 (key 0 handled in oproj).
// K staged pair-transposed: ktp[p][d] = {K_{2p}[d], K_{2p+1}[d]} so one
// v_pk_fma_f32 advances the score of TWO keys at once.
__global__ __launch_bounds__(256, 6) void k_attn(const float* __restrict__ qkv,
    float* __restrict__ LP, float4* __restrict__ AP) {
  int tid = threadIdx.x;
  int h = blockIdx.y;
  int c = blockIdx.z;
  int kbase = 1 + c * 256;
  size_t base = ((size_t)c * NHEAD + h) * LL;

  if (blockIdx.x == 8) {
    // ---- q=4096: 256 lanes take one key each, LDS-reduce ----
    __shared__ float rl[256];
    __shared__ float4 ra[256];
    float4 q = *(const float4*)(qkv + (size_t)4096 * 96 + h * HD);
    q.x *= QSCALE; q.y *= QSCALE; q.z *= QSCALE; q.w *= QSCALE;
    float4 kv = *(const float4*)(qkv + (size_t)(kbase + tid) * 96 + 32 + h * HD);
    float4 vv = *(const float4*)(qkv + (size_t)(kbase + tid) * 96 + 64 + h * HD);
    float p = EXP2(dot4(q, kv));
    rl[tid] = p;
    ra[tid] = make_float4(p * vv.x, p * vv.y, p * vv.z, p * vv.w);
    __syncthreads();
    for (int s = 128; s > 0; s >>= 1) {
      if (tid < s) {
        rl[tid] += rl[tid + s];
        ra[tid].x += ra[tid + s].x;
        ra[tid].y += ra[tid + s].y;
        ra[tid].z += ra[tid + s].z;
        ra[tid].w += ra[tid + s].w;
      }
      __syncthreads();
    }
    if (tid == 0) {
      LP[base + 4096] = rl[0];
      AP[base + 4096] = ra[0];
    }
    return;
  }

  // ---- main path: 512 queries per block, 256 keys per chunk ----
  __shared__ float ktp[128 * 8];   // 128 key-pairs x {d0..d3}x{lo,hi}
  __shared__ float4 vt[256];
  {
    float4 kv = *(const float4*)(qkv + (size_t)(kbase + tid) * 96 + 32 + h * HD);
    float* bp = ktp + (tid >> 1) * 8 + (tid & 1);
    bp[0] = kv.x; bp[2] = kv.y; bp[4] = kv.z; bp[6] = kv.w;
    vt[tid] = *(const float4*)(qkv + (size_t)(kbase + tid) * 96 + 64 + h * HD);
  }

  v2f qb2[QB][4];
  v2f l2[QB], a01[QB], a23[QB];
  int q0 = blockIdx.x * 512 + tid;
#pragma unroll
  for (int i = 0; i < QB; ++i) {
    int q = q0 + i * 256;
    float4 t = *(const float4*)(qkv + (size_t)q * 96 + h * HD);
    t.x *= QSCALE; t.y *= QSCALE; t.z *= QSCALE; t.w *= QSCALE;
    qb2[i][0] = (v2f){t.x, t.x};
    qb2[i][1] = (v2f){t.y, t.y};
    qb2[i][2] = (v2f){t.z, t.z};
    qb2[i][3] = (v2f){t.w, t.w};
    l2[i] = (v2f){0.f, 0.f};
    a01[i] = (v2f){0.f, 0.f};
    a23[i] = (v2f){0.f, 0.f};
  }
  __syncthreads();

  const v2f* vv2 = (const v2f*)vt;
#pragma unroll 2
  for (int p = 0; p < 128; ++p) {
    const v2f* kp = (const v2f*)(ktp + p * 8);
    v2f kp0 = kp[0], kp1 = kp[1], kp2 = kp[2], kp3 = kp[3];
    v2f va01 = vv2[4 * p + 0], va23 = vv2[4 * p + 1];
    v2f vb01 = vv2[4 * p + 2], vb23 = vv2[4 * p + 3];
#pragma unroll
    for (int i = 0; i < QB; ++i) {
      v2f s2 = qb2[i][0] * kp0;
      s2 = FMA2(qb2[i][1], kp1, s2);
      s2 = FMA2(qb2[i][2], kp2, s2);
      s2 = FMA2(qb2[i][3], kp3, s2);
      v2f pv;
      pv.x = EXP2(s2.x);
      pv.y = EXP2(s2.y);
      l2[i] += pv;
      v2f pa = pv.xx;
      v2f pb = pv.yy;
      a01[i] = FMA2(pa, va01, a01[i]);
      a23[i] = FMA2(pa, va23, a23[i]);
      a01[i] = FMA2(pb, vb01, a01[i]);
      a23[i] = FMA2(pb, vb23, a23[i]);
    }
  }

#pragma unroll
  for (int i = 0; i < QB; ++i) {
    size_t idx = base + q0 + i * 256;
    LP[idx] = l2[i].x + l2[i].y;
    AP[idx] = make_float4(a01[i].x, a01[i].y, a23[i].x, a23[i].y);
  }
}

// ------- fused: sum split-K partials + analytic key-0 + o-proj + LN1 --------
// 256 thr = 8 rows x 32 lanes. Lane ch = h*4+d.
__global__ __launch_bounds__(256) void k_oproj(const float* __restrict__ LP,
    const float4* __restrict__ AP, const float* __restrict__ qkv,
    float* __restrict__ x, const float* __restrict__ ow,
    const float* __restrict__ ob, const float* __restrict__ g,
    const float* __restrict__ bln) {
  int tid = threadIdx.x;
  int r = tid >> 5, ch = tid & 31;
  int row = blockIdx.x * 8 + r;
  __shared__ float os[8][32];
  bool ok = row < LL;
  if (ok) {
    int h = ch >> 2, d = ch & 3;
    float L = 0.f, A = 0.f;
#pragma unroll
    for (int c = 0; c < NCHUNK; ++c) {
      size_t idx = ((size_t)c * NHEAD + h) * LL + row;
      L += LP[idx];
      A += ((const float*)&AP[idx])[d];
    }
    // key 0 (CLS key) analytic term
    float4 q4 = *(const float4*)(qkv + (size_t)row * 96 + h * HD);
    float4 k04 = *(const float4*)(qkv + 32 + h * HD);
    float p0 = EXP2(QSCALE * dot4(q4, k04));
    L += p0;
    A = fmaf(p0, qkv[64 + h * HD + d], A);
    os[r][ch] = A / L;
  } else {
    os[r][ch] = 0.f;
  }
  __syncthreads();
  float acc = 0.f;
#pragma unroll
  for (int k = 0; k < 32; ++k) acc = fmaf(os[r][k], ow[ch * 32 + k], acc);
  float val = ok ? (x[(size_t)row * HDIM + ch] + acc + ob[ch]) : 0.f;
  float mean = val;
#pragma unroll
  for (int off = 16; off > 0; off >>= 1) mean += __shfl_xor(mean, off, 32);
  mean *= (1.f / 32.f);
  float d2 = val - mean;
  float var = d2 * d2;
#pragma unroll
  for (int off = 16; off > 0; off >>= 1) var += __shfl_xor(var, off, 32);
  var *= (1.f / 32.f);
  float y = d2 / sqrtf(var + EPSLN) * g[ch] + bln[ch];
  if (ok) x[(size_t)row * HDIM + ch] = y;
}

// ---------------- fused FFN part A: per (row-tile, f-segment) ----------------
__global__ __launch_bounds__(256) void k_ffnA(const float* __restrict__ x,
    const float* __restrict__ w1, const float* __restrict__ b1,
    const float* __restrict__ w2, float* __restrict__ part2) {
  __shared__ float Xs[RT][33];
  __shared__ float W1t[32][132];
  __shared__ float W2t[FS][36];
  __shared__ float Fs[RT][129];
  int tid = threadIdx.x;
  int r0 = blockIdx.x * RT;
  int f0 = blockIdx.y * FS;

#pragma unroll
  for (int p = 0; p < 8; ++p) {
    int idx = p * 256 + tid;
    int r = idx >> 5, k = idx & 31;
    Xs[r][k] = (r0 + r < LL) ? x[(size_t)(r0 + r) * HDIM + k] : 0.f;
  }
#pragma unroll
  for (int p = 0; p < 16; ++p) {
    int idx = p * 256 + tid;
    int c = idx >> 5, k = idx & 31;
    W1t[k][c] = w1[(size_t)(f0 + c) * HDIM + k];
  }
#pragma unroll
  for (int p = 0; p < 16; ++p) {
    int idx = p * 256 + tid;
    int c = idx >> 7, k = idx & 127;
    W2t[k][c] = w2[(size_t)c * FFD + f0 + k];
  }
  __syncthreads();

  int rg = tid >> 4, cg = tid & 15;
  float acc[4][8];
#pragma unroll
  for (int i = 0; i < 4; ++i)
#pragma unroll
    for (int j = 0; j < 8; ++j) acc[i][j] = 0.f;
#pragma unroll
  for (int k = 0; k < 32; ++k) {
    float xv[4];
#pragma unroll
    for (int i = 0; i < 4; ++i) xv[i] = Xs[rg * 4 + i][k];
    float4 w0 = *(const float4*)&W1t[k][cg * 8];
    float4 w1v = *(const float4*)&W1t[k][cg * 8 + 4];
#pragma unroll
    for (int i = 0; i < 4; ++i) {
      acc[i][0] = fmaf(xv[i], w0.x, acc[i][0]);
      acc[i][1] = fmaf(xv[i], w0.y, acc[i][1]);
      acc[i][2] = fmaf(xv[i], w0.z, acc[i][2]);
      acc[i][3] = fmaf(xv[i], w0.w, acc[i][3]);
      acc[i][4] = fmaf(xv[i], w1v.x, acc[i][4]);
      acc[i][5] = fmaf(xv[i], w1v.y, acc[i][5]);
      acc[i][6] = fmaf(xv[i], w1v.z, acc[i][6]);
      acc[i][7] = fmaf(xv[i], w1v.w, acc[i][7]);
    }
  }
#pragma unroll
  for (int j = 0; j < 8; ++j) {
    float bb = b1[f0 + cg * 8 + j];
#pragma unroll
    for (int i = 0; i < 4; ++i)
      Fs[rg * 4 + i][cg * 8 + j] = fmaxf(acc[i][j] + bb, 0.f);
  }
  __syncthreads();

  int kq = tid >> 6, r4 = (tid >> 2) & 15, c8 = tid & 3;
  float a2[4][8];
#pragma unroll
  for (int i = 0; i < 4; ++i)
#pragma unroll
    for (int j = 0; j < 8; ++j) a2[i][j] = 0.f;
  int kbase = kq * 32;
#pragma unroll
  for (int kk = 0; kk < 32; ++kk) {
    int k = kbase + kk;
    float fv[4];
#pragma unroll
    for (int i = 0; i < 4; ++i) fv[i] = Fs[r4 * 4 + i][k];
    float4 u0 = *(const float4*)&W2t[k][c8 * 8];
    float4 u1 = *(const float4*)&W2t[k][c8 * 8 + 4];
#pragma unroll
    for (int i = 0; i < 4; ++i) {
      a2[i][0] = fmaf(fv[i], u0.x, a2[i][0]);
      a2[i][1] = fmaf(fv[i], u0.y, a2[i][1]);
      a2[i][2] = fmaf(fv[i], u0.z, a2[i][2]);
      a2[i][3] = fmaf(fv[i], u0.w, a2[i][3]);
      a2[i][4] = fmaf(fv[i], u1.x, a2[i][4]);
      a2[i][5] = fmaf(fv[i], u1.y, a2[i][5]);
      a2[i][6] = fmaf(fv[i], u1.z, a2[i][6]);
      a2[i][7] = fmaf(fv[i], u1.w, a2[i][7]);
    }
  }
  for (int q = 0; q < 4; ++q) {
    if (kq == q) {
#pragma unroll
      for (int i = 0; i < 4; ++i)
#pragma unroll
        for (int j = 0; j < 8; ++j) {
          int rr = r4 * 4 + i, cc = c8 * 8 + j;
          if (q == 0) Xs[rr][cc] = a2[i][j];
          else Xs[rr][cc] += a2[i][j];
        }
    }
    __syncthreads();
  }
#pragma unroll
  for (int p = 0; p < 8; ++p) {
    int idx = p * 256 + tid;
    int r = idx >> 5, cc = idx & 31;
    if (r0 + r < LL)
      part2[((size_t)blockIdx.y * LL + r0 + r) * HDIM + cc] = Xs[r][cc];
  }
}

// ------ FFN part B: combine segments + residual + LN2, fused next-layer qkv --
__global__ __launch_bounds__(256) void k_ffnB_qkv(float* __restrict__ x,
    const float* __restrict__ part2, const float* __restrict__ b2,
    const float* __restrict__ g, const float* __restrict__ bln,
    const float* __restrict__ qw, const float* __restrict__ qb,
    float* __restrict__ qkv, int do_qkv) {
  __shared__ float xs[8][33];
  int tid = threadIdx.x;
  int r = tid >> 5, ch = tid & 31;
  int row = blockIdx.x * 8 + r;
  bool ok = row < LL;
  float s = 0.f;
  if (ok) {
#pragma unroll
    for (int q = 0; q < NFS; ++q)
      s += part2[((size_t)q * LL + row) * HDIM + ch];
  }
  float val = ok ? (x[(size_t)row * HDIM + ch] + s + b2[ch]) : 0.f;
  float mean = val;
#pragma unroll
  for (int off = 16; off > 0; off >>= 1) mean += __shfl_xor(mean, off, 32);
  mean *= (1.f / 32.f);
  float d = val - mean;
  float var = d * d;
#pragma unroll
  for (int off = 16; off > 0; off >>= 1) var += __shfl_xor(var, off, 32);
  var *= (1.f / 32.f);
  float y = d / sqrtf(var + EPSLN) * g[ch] + bln[ch];
  if (ok) x[(size_t)row * HDIM + ch] = y;
  xs[r][ch] = ok ? y : 0.f;
  __syncthreads();
  if (!do_qkv || !ok) return;
#pragma unroll
  for (int t3 = 0; t3 < 3; ++t3) {
    int cc = t3 * 32 + ch;
    const float4* wr = (const float4*)(qw + (size_t)cc * HDIM);
    float acc = qb[cc];
#pragma unroll
    for (int k = 0; k < 8; ++k) {
      float4 wv = wr[k];
      acc = fmaf(xs[r][4 * k + 0], wv.x, acc);
      acc = fmaf(xs[r][4 * k + 1], wv.y, acc);
      acc = fmaf(xs[r][4 * k + 2], wv.z, acc);
      acc = fmaf(xs[r][4 * k + 3], wv.w, acc);
    }
    qkv[(size_t)row * 96 + cc] = acc;
  }
}

// ---------------- final: sigmoid(x[0] . cls_w + cls_b) -----------------------
__global__ void k_final(const float* __restrict__ x, const float* __restrict__ cw,
                        const float* __restrict__ cb, float* __restrict__ out) {
  int t = threadIdx.x;   // 64 threads
  float v = (t < 32) ? x[t] * cw[t] : 0.f;
#pragma unroll
  for (int off = 32; off > 0; off >>= 1) v += __shfl_xor(v, off, 64);
  if (t == 0) {
    float z = v + cb[0];
    out[0] = 1.f / (1.f + expf(-z));
  }
}

extern "C" void kernel_launch(void* const* d_in, const int* in_sizes, int n_in,
                              void* d_out, int out_size, void* d_ws, size_t ws_size,
                              hipStream_t stream) {
  const float* data  = (const float*)d_in[0];
  const float* lin_w = (const float*)d_in[1];
  const float* lin_b = (const float*)d_in[2];
  const float* qkv_w = (const float*)d_in[3];
  const float* qkv_b = (const float*)d_in[4];
  const float* out_w = (const float*)d_in[5];
  const float* out_b = (const float*)d_in[6];
  const float* ln1_g = (const float*)d_in[7];
  const float* ln1_b = (const float*)d_in[8];
  const float* ff1_w = (const float*)d_in[9];
  const float* ff1_b = (const float*)d_in[10];
  const float* ff2_w = (const float*)d_in[11];
  const float* ff2_b = (const float*)d_in[12];
  const float* ln2_g = (const float*)d_in[13];
  const float* ln2_b = (const float*)d_in[14];
  const float* cls_w = (const float*)d_in[15];
  const float* cls_b = (const float*)d_in[16];

  float* ws = (float*)d_ws;
  float*  X   = ws;                            // LL*32
  float*  QKV = X + (size_t)LL * 32;           // LL*96
  float4* AP  = (float4*)(QKV + (size_t)LL * 96);  // NCHUNK*NHEAD*LL float4
  float*  LP  = (float*)(AP + (size_t)NCHUNK * NHEAD * LL);  // NCHUNK*NHEAD*LL
  float*  PART2 = (float*)AP;                  // aliased: disjoint lifetimes

  const int NROWB = (LL + 7) / 8;              // 513

  k_embed_qkv<<<NROWB, 256, 0, stream>>>(data, lin_w, lin_b, X,
                                         qkv_w, qkv_b, QKV);
  for (int l = 0; l < NLAYER; ++l) {
    k_attn<<<dim3(9, NHEAD, NCHUNK), 256, 0, stream>>>(QKV, LP, AP);
    k_oproj<<<NROWB, 256, 0, stream>>>(
        LP, AP, QKV, X, out_w + (size_t)l * 32 * 32, out_b + (size_t)l * 32,
        ln1_g + (size_t)l * 32, ln1_b + (size_t)l * 32);
    k_ffnA<<<dim3((LL + RT - 1) / RT, NFS), 256, 0, stream>>>(
        X, ff1_w + (size_t)l * FFD * 32, ff1_b + (size_t)l * FFD,
        ff2_w + (size_t)l * 32 * FFD, PART2);
    int nl = l + 1;
    int do_qkv = (nl < NLAYER) ? 1 : 0;
    const float* qw = qkv_w + (size_t)(do_qkv ? nl : 0) * 96 * 32;
    const float* qb = qkv_b + (size_t)(do_qkv ? nl : 0) * 96;
    k_ffnB_qkv<<<NROWB, 256, 0, stream>>>(
        X, PART2, ff2_b + (size_t)l * 32,
        ln2_g + (size_t)l * 32, ln2_b + (size_t)l * 32,
        qw, qb, QKV, do_qkv);
  }
  k_final<<<1, 64, 0, stream>>>(X, cls_w, cls_b, (float*)d_out);
}